// Round 4
// baseline (418.091 us; speedup 1.0000x reference)
//
#include <hip/hip_runtime.h>
#include <hip/hip_bf16.h>

#define S 2048
#define DM 2048
#define NH 16
#define DH 128

typedef __attribute__((ext_vector_type(8))) short short8;
typedef __attribute__((ext_vector_type(4))) float floatx4;
typedef unsigned short u16;
typedef unsigned int u32;

__device__ __forceinline__ u16 f2bf(float f) {
  union { float f; u32 u; } v; v.f = f;
  u32 r = v.u + 0x7fffu + ((v.u >> 16) & 1u);
  return (u16)(r >> 16);
}
// HW packed round-to-nearest-even f32x2 -> bf16x2 (v_cvt_pk_bf16_f32)
__device__ __forceinline__ u32 pack2(float lo, float hi) {
  float2 f; f.x = lo; f.y = hi;
  __hip_bfloat162 h = __float22bfloat162_rn(f);
  union { __hip_bfloat162 h; u32 u; } c; c.h = h;
  return c.u;
}

__device__ __forceinline__ floatx4 mfma16(short8 a, short8 b, floatx4 c) {
  return __builtin_amdgcn_mfma_f32_16x16x32_bf16(a, b, c, 0, 0, 0);
}

// async global -> LDS, 16B per lane. LDS dest = wave-uniform base + lane*16.
__device__ __forceinline__ void async_cp16(const u16* g, u16* l) {
  __builtin_amdgcn_global_load_lds(
      (const __attribute__((address_space(1))) void*)g,
      (__attribute__((address_space(3))) void*)l, 16, 0, 0);
}

// ---------- convert x (fp32 -> bf16), 4 elems/thread ----------
__global__ void conv_x_k(const float* __restrict__ x, u16* __restrict__ xb) {
  int gid = blockIdx.x * 256 + threadIdx.x;
  float4 v = ((const float4*)x)[gid];
  uint2 p; p.x = pack2(v.x, v.y); p.y = pack2(v.z, v.w);
  ((uint2*)xb)[gid] = p;
}

// ---------- transpose+convert weights: Wt[n*2048+k] = bf16(W[k*2048+n]) ----------
__global__ void conv_w_k(const float* __restrict__ W0, const float* __restrict__ W1,
                         const float* __restrict__ W2, const float* __restrict__ W3,
                         u16* __restrict__ out) {
  __shared__ float tile[32][33];
  const float* W = blockIdx.z == 0 ? W0 : blockIdx.z == 1 ? W1 : blockIdx.z == 2 ? W2 : W3;
  u16* O = out + (size_t)blockIdx.z * DM * DM;
  int tx = threadIdx.x & 31, ty = threadIdx.x >> 5;
  int k0 = blockIdx.y * 32, n0 = blockIdx.x * 32;
#pragma unroll
  for (int j = 0; j < 4; j++)
    tile[ty + j * 8][tx] = W[(size_t)(k0 + ty + j * 8) * DM + n0 + tx];
  __syncthreads();
#pragma unroll
  for (int j = 0; j < 4; j++)
    O[(size_t)(n0 + ty + j * 8) * DM + k0 + tx] = f2bf(tile[tx][ty + j * 8]);
}

// ---------- 128x256 bf16 MFMA GEMM, phase-balanced pipeline ----------
// 4 waves, each owns a 128(m) x 64(n) sub-tile (8 m-frags x 4 n-frags):
// 24 ds_read_b128 per 64 MFMA per K-tile (reads*12cy < MFMA*4.85cy -> the
// matrix pipe's queued backlog covers the next phase's read window).
// 4 phases/K-tile: ph1 {A(m0-3,k0)+B(k0): 8 rd, 16 MFMA}, ph2 {A(m4-7,k0):
// 4 rd}, ph3 {A(m0-3,k1)+B(k1): 8 rd}, ph4 {A(m4-7,k1): 4 rd}.
// Staging: 12 async 16B loads/thread/tile in queue order [B j0..7, A j0..3],
// 3 per phase, one tile ahead into the other buffer. Waits: vmcnt(3) at
// ph1-end (A-half1 ready for ph2), vmcnt(2) at tile boundary (keep A-half1
// of next tile in flight). Never drains vmcnt to 0 in steady state.
// LDS swizzle: stored granule g holds source granule g^(row&7); reads use
// ((ks*4+quad)^(l16&7)) -> 2 lanes/bank within 16-lane groups (free).
// Grid fill exact: QKV 8x32x3 = 768 = 3 rounds @1 block/CU; O-proj 256 = 1.
#define BM 128
#define BN 256
#define BK 64
#define NT (DM / BK)   // 32 K-tiles

#define BARRIER __builtin_amdgcn_s_barrier()
#define SB __builtin_amdgcn_sched_barrier(0)
#define LGKM0 asm volatile("s_waitcnt lgkmcnt(0)" ::: "memory")

#define STG_B(q, j, koff) \
  async_cp16(pBg + (size_t)(j) * 32 * DM + (koff), &Bs[q][so + (j) * 2048])
#define STG_A(q, j, koff) \
  async_cp16(pAg + (size_t)(j) * 32 * DM + (koff), &As[q][so + (j) * 2048])

#define MFMA4(mi, av) \
    acc[mi][0] = mfma16(av, b0, acc[mi][0]); \
    acc[mi][1] = mfma16(av, b1, acc[mi][1]); \
    acc[mi][2] = mfma16(av, b2, acc[mi][2]); \
    acc[mi][3] = mfma16(av, b3, acc[mi][3]);

#define PH1(p, q, koff, PRE) { \
    a0 = *(const short8*)&As[p][arow + xk0]; \
    a1 = *(const short8*)&As[p][1024 + arow + xk0]; \
    a2 = *(const short8*)&As[p][2048 + arow + xk0]; \
    a3 = *(const short8*)&As[p][3072 + arow + xk0]; \
    b0 = *(const short8*)&Bs[p][brow + xk0]; \
    b1 = *(const short8*)&Bs[p][1024 + brow + xk0]; \
    b2 = *(const short8*)&Bs[p][2048 + brow + xk0]; \
    b3 = *(const short8*)&Bs[p][3072 + brow + xk0]; \
    if (PRE) { STG_B(q, 0, koff); STG_B(q, 1, koff); STG_B(q, 2, koff); } \
    BARRIER; LGKM0; SB; \
    __builtin_amdgcn_s_setprio(1); \
    MFMA4(0, a0) MFMA4(1, a1) MFMA4(2, a2) MFMA4(3, a3) \
    __builtin_amdgcn_s_setprio(0); SB; \
    if (PRE) { asm volatile("s_waitcnt vmcnt(3)" ::: "memory"); } \
    else     { asm volatile("s_waitcnt vmcnt(0)" ::: "memory"); } \
    BARRIER; }

#define PH2(p, q, koff, PRE) { \
    a0 = *(const short8*)&As[p][4096 + arow + xk0]; \
    a1 = *(const short8*)&As[p][5120 + arow + xk0]; \
    a2 = *(const short8*)&As[p][6144 + arow + xk0]; \
    a3 = *(const short8*)&As[p][7168 + arow + xk0]; \
    if (PRE) { STG_B(q, 3, koff); STG_B(q, 4, koff); STG_B(q, 5, koff); } \
    BARRIER; LGKM0; SB; \
    __builtin_amdgcn_s_setprio(1); \
    MFMA4(4, a0) MFMA4(5, a1) MFMA4(6, a2) MFMA4(7, a3) \
    __builtin_amdgcn_s_setprio(0); \
    BARRIER; }

#define PH3(p, q, koff, PRE) { \
    a0 = *(const short8*)&As[p][arow + xk1]; \
    a1 = *(const short8*)&As[p][1024 + arow + xk1]; \
    a2 = *(const short8*)&As[p][2048 + arow + xk1]; \
    a3 = *(const short8*)&As[p][3072 + arow + xk1]; \
    b0 = *(const short8*)&Bs[p][brow + xk1]; \
    b1 = *(const short8*)&Bs[p][1024 + brow + xk1]; \
    b2 = *(const short8*)&Bs[p][2048 + brow + xk1]; \
    b3 = *(const short8*)&Bs[p][3072 + brow + xk1]; \
    if (PRE) { STG_B(q, 6, koff); STG_B(q, 7, koff); STG_A(q, 0, koff); } \
    BARRIER; LGKM0; SB; \
    __builtin_amdgcn_s_setprio(1); \
    MFMA4(0, a0) MFMA4(1, a1) MFMA4(2, a2) MFMA4(3, a3) \
    __builtin_amdgcn_s_setprio(0); \
    BARRIER; }

#define PH4(p, q, koff, PRE, LAST) { \
    a0 = *(const short8*)&As[p][4096 + arow + xk1]; \
    a1 = *(const short8*)&As[p][5120 + arow + xk1]; \
    a2 = *(const short8*)&As[p][6144 + arow + xk1]; \
    a3 = *(const short8*)&As[p][7168 + arow + xk1]; \
    if (PRE) { STG_A(q, 1, koff); STG_A(q, 2, koff); STG_A(q, 3, koff); } \
    BARRIER; LGKM0; SB; \
    __builtin_amdgcn_s_setprio(1); \
    MFMA4(4, a0) MFMA4(5, a1) MFMA4(6, a2) MFMA4(7, a3) \
    __builtin_amdgcn_s_setprio(0); SB; \
    if (!LAST) { asm volatile("s_waitcnt vmcnt(2)" ::: "memory"); BARRIER; SB; } }

#define TILE(p, q, koff, PRE, LAST) \
    PH1(p, q, koff, PRE) PH2(p, q, koff, PRE) PH3(p, q, koff, PRE) \
    PH4(p, q, koff, PRE, LAST)

__global__ __launch_bounds__(256, 1)
void gemm_k(const u16* __restrict__ A, const u16* __restrict__ Wt,
            u16* __restrict__ oQ, u16* __restrict__ oK, u16* __restrict__ oV,
            float* __restrict__ oO, const int* __restrict__ tp, int opmode)
{
  __shared__ u16 As[2][BM * BK];   // 2 x 16 KiB
  __shared__ u16 Bs[2][BN * BK];   // 2 x 32 KiB  -> 96 KiB total
  const int t = threadIdx.x;
  const int w = t >> 6, lane = t & 63;
  const int l16 = lane & 15, quad = lane >> 4;
  // remap so 32 consecutive blocks share one B panel (L2 reuse within XCD)
  const int bid = blockIdx.y * 8 + blockIdx.x;
  const int m0 = (bid & 31) * BM, n0 = (bid >> 5) * BN;
  const u16* Bt = Wt + (size_t)(opmode == 1 ? 3 : blockIdx.z) * DM * DM;

  // staging: unit u = t + j*256 -> row u>>3, stored granule u&7 holds source
  // granule (u&7)^(row&7). Both t&7 and (t>>3)&7 are j-invariant.
  const int srow = t >> 3;
  const int sc = ((t & 7) ^ (srow & 7)) * 8;
  const u16* pAg = A + (size_t)(m0 + srow) * DM + sc;
  const u16* pBg = Bt + (size_t)(n0 + srow) * DM + sc;
  const int so = t * 8;

  // fragment read offsets (u16 units); row&7 == l16&7 (row bases mult. of 16)
  const int arow = l16 * 64;
  const int brow = w * 4096 + l16 * 64;
  const int xk0 = ((quad) ^ (l16 & 7)) << 3;
  const int xk1 = ((4 + quad) ^ (l16 & 7)) << 3;

  floatx4 acc[8][4] = {};
  short8 a0, a1, a2, a3, b0, b1, b2, b3;

  // ---- prologue: tile 0 -> buf0 in queue order; keep A-half1 in flight
#pragma unroll
  for (int j = 0; j < 8; j++) STG_B(0, j, 0);
#pragma unroll
  for (int j = 0; j < 4; j++) STG_A(0, j, 0);
  SB;
  asm volatile("s_waitcnt vmcnt(2)" ::: "memory");
  BARRIER; SB;

  for (int it = 0; it < 15; ++it) {
    const int kA = it * 128 + 64;        // tile 2it+1 -> buf1
    const int kB = it * 128 + 128;       // tile 2it+2 -> buf0
    TILE(0, 1, kA, 1, 0)
    TILE(1, 0, kB, 1, 0)
  }
  TILE(0, 1, 31 * 64, 1, 0)              // tile 30, stages tile 31
  TILE(1, 0, 0, 0, 1)                    // tile 31, no staging

  // ---- epilogue: per-wave 128x64 tile; m = mi*16+quad*4+r, n = w*64+ni*16+l16
  const int mode = (opmode == 1) ? 3 : ((int)blockIdx.z == 2 ? 2 : 0);
  const int nbase = n0 + w * 64;
  if (mode == 3) {
#pragma unroll
    for (int mi = 0; mi < 8; mi++) {
      int m = m0 + mi * 16 + quad * 4;
#pragma unroll
      for (int ni = 0; ni < 4; ni++) {
        int n = nbase + ni * 16 + l16;
#pragma unroll
        for (int r = 0; r < 4; r++)
          oO[(size_t)(m + r) * DM + n] = acc[mi][ni][r];
      }
    }
  } else if (mode == 2) {
#pragma unroll
    for (int mi = 0; mi < 8; mi++) {
      int m = m0 + mi * 16 + quad * 4;
      int b = m >> 11, s = m & (S - 1);
#pragma unroll
      for (int ni = 0; ni < 4; ni++) {
        int f = nbase + ni * 16 + l16;
        int h = f >> 7, dh = f & (DH - 1);
        uint2 pk; pk.x = pack2(acc[mi][ni][0], acc[mi][ni][1]);
        pk.y = pack2(acc[mi][ni][2], acc[mi][ni][3]);
        *(uint2*)&oV[((size_t)(b * NH + h) * DH + dh) * S + s] = pk;
      }
    }
  } else {
    // RoPE fused; for Q (z==0) also fold 1/sqrt(dk)*log2(e) into the value
    u16* Out = ((int)blockIdx.z == 0) ? oQ : oK;
    const float qs = ((int)blockIdx.z == 0) ? 0.12752780f : 1.0f;
#pragma unroll
    for (int mi = 0; mi < 8; mi++) {
#pragma unroll
      for (int r = 0; r < 4; r++) {
        int m = m0 + mi * 16 + quad * 4 + r;
        int b = m >> 11, s = m & (S - 1);
        int ps = tp[s];
#pragma unroll
        for (int ni = 0; ni < 4; ni++) {
          int f = nbase + ni * 16 + l16;
          int h = f >> 7, dh = f & (DH - 1);
          float own = acc[mi][ni][r];
          float oth = __shfl_xor(own, 1, 64);
          float fr = __expf((float)(dh & ~1) * (-9.210340371976184f / 128.0f));
          float ang = (float)ps * fr;
          float sn, cs; __sincosf(ang, &sn, &cs);
          float res = (dh & 1) ? (oth * sn + own * cs) : (own * cs - oth * sn);
          Out[((size_t)(b * NH + h) * S + s) * DH + dh] = f2bf(res * qs);
        }
      }
    }
  }
}

// ---------- causal flash attention v7: 16 q/wave, fixed-base softmax, 40KB LDS ----------
// P is unpadded (16x64) with 16B-granule XOR swizzle -> Ks+Vs+P = 40960 B exactly,
// 4 blocks/CU at __launch_bounds__(256,4). Fixed-base softmax as v6.
__global__ __launch_bounds__(256, 4)
void attn_k(const u16* __restrict__ Q, const u16* __restrict__ K,
            const u16* __restrict__ Vt, u16* __restrict__ O)
{
  __shared__ u16 Ks[64 * 128];   // key-major, swizzle: unit r*16 + (c ^ (r&15))
  __shared__ u16 Vs[128 * 64];   // dh-major,  swizzle: unit r*8  + (c ^ (r&7))
  __shared__ u16 P[4][16 * 64];  // per-wave 16 q x 64 keys, 16B-XOR-swizzled
  const int t = threadIdx.x, w = t >> 6, lane = t & 63;
  const int l16 = lane & 15, quad = lane >> 4;
  const int task = blockIdx.x;
  const int bh = task & 31, b = bh >> 4, h = bh & 15;
  const int g = 31 - (task >> 5);        // big groups dispatch first (LPT)
  const int qg = g * 64;
  const int qt = qg + w * 16;
  const u16* Qb = Q + (size_t)bh * S * DH;
  const u16* Kb = K + (size_t)bh * S * DH;
  const u16* Vb = Vt + (size_t)bh * DH * S;
  u16* Pw = P[w];
  const int pxor = l16 & 7;

  const u16* pK[4]; u16* lK[4];
  const u16* pV[4]; u16* lV[4];
#pragma unroll
  for (int j = 0; j < 4; j++) {
    int kr = w * 16 + j * 4 + (lane >> 4);
    int ks = lane & 15;
    int kc = ks ^ (kr & 15);
    pK[j] = Kb + (size_t)kr * DH + kc * 8;
    lK[j] = &Ks[kr * 128 + ks * 8];
    int vr = w * 32 + j * 8 + (lane >> 3);
    int vs = lane & 7;
    int vc = vs ^ (vr & 7);
    pV[j] = Vb + (size_t)vr * S + vc * 8;
    lV[j] = &Vs[vr * 64 + vs * 8];
  }

  short8 aq[4];
#pragma unroll
  for (int kc = 0; kc < 4; kc++)
    aq[kc] = *(const short8*)&Qb[(size_t)(qt + l16) * DH + kc * 32 + quad * 8];

  floatx4 o[8] = {};
  float lsum = 0.0f;                 // per-lane partial: keys in own quad-subset
  const int kend = qg + 64;

  for (int k0 = 0; k0 < kend; k0 += 64) {
#pragma unroll
    for (int j = 0; j < 4; j++) async_cp16(pK[j] + (size_t)k0 * DH, lK[j]);
#pragma unroll
    for (int j = 0; j < 4; j++) async_cp16(pV[j] + k0, lV[j]);
    __syncthreads();

    // ---- S^T = K·Q^T : sc[hh] row = key k0+hh*16+quad*4+r, col = q = l16
    floatx4 sc[4] = {};
#pragma unroll
    for (int hh = 0; hh < 4; hh++) {
      int row = hh * 16 + l16;
#pragma unroll
      for (int kc = 0; kc < 4; kc++) {
        short8 kf = *(short8*)&Ks[row * 128 + (((kc * 4 + quad) ^ l16) << 3)];
        sc[hh] = mfma16(kf, aq[kc], sc[hh]);
      }
    }
    // ---- causal mask (only the diagonal-overlapping tile)
    if (k0 + 64 > qt) {
#pragma unroll
      for (int hh = 0; hh < 4; hh++)
#pragma unroll
        for (int r = 0; r < 4; r++) {
          int j = k0 + hh * 16 + quad * 4 + r;
          if (j > qt + l16) sc[hh][r] = -3.0e38f;
        }
    }
    // ---- direct exp2 softmax numerator; per-lane l accumulation
#pragma unroll
    for (int hh = 0; hh < 4; hh++) {
      float e0 = __builtin_amdgcn_exp2f(fminf(sc[hh][0], 44.0f));
      float e1 = __builtin_amdgcn_exp2f(fminf(sc[hh][1], 44.0f));
      float e2 = __builtin_amdgcn_exp2f(fminf(sc[hh][2], 44.0f));
      float e3 = __builtin_amdgcn_exp2f(fminf(sc[hh][3], 44.0f));
      lsum += (e0 + e1) + (e2 + e3);
      uint2 pk; pk.x = pack2(e0, e1); pk.y = pack2(e2, e3);
      // write keys hh*16+quad*4..+3 of row q=l16: 16B-unit u = 2hh + quad/2,
      // swizzled u^pxor, 8B half (quad&1)
      int su = (2 * hh + (quad >> 1)) ^ pxor;
      *(uint2*)&Pw[l16 * 64 + su * 8 + (quad & 1) * 4] = pk;
    }
    asm volatile("s_waitcnt lgkmcnt(0)" ::: "memory");
    // ---- O^T += V^T · P^T
#pragma unroll
    for (int c = 0; c < 2; c++) {
      // read keys c*32+quad*8..+7 of row l16: 16B-unit u = 4c+quad, swizzled
      short8 pf = *(short8*)&Pw[l16 * 64 + (((4 * c + quad) ^ pxor) << 3)];
#pragma unroll
      for (int t8 = 0; t8 < 8; t8++) {
        int row = t8 * 16 + l16;
        short8 av = *(short8*)&Vs[row * 64 + (((c * 4 + quad) ^ (l16 & 7)) << 3)];
        o[t8] = mfma16(av, pf, o[t8]);
      }
    }
    __syncthreads();
  }

  // ---- epilogue: reduce l across quads ONCE, then scale and store
  float l = lsum + __shfl_xor(lsum, 16, 64);
  l += __shfl_xor(l, 32, 64);
  float inv = __builtin_amdgcn_rcpf(l);
#pragma unroll
  for (int t8 = 0; t8 < 8; t8++) {
    uint2 pa;
    pa.x = pack2(o[t8][0] * inv, o[t8][1] * inv);
    pa.y = pack2(o[t8][2] * inv, o[t8][3] * inv);
    *(uint2*)&O[((size_t)(b * S + qt + l16)) * DM + h * DH + t8 * 16 + quad * 4] = pa;
  }
}

extern "C" void kernel_launch(void* const* d_in, const int* in_sizes, int n_in,
                              void* d_out, int out_size, void* d_ws, size_t ws_size,
                              hipStream_t stream) {
  const float* x  = (const float*)d_in[0];
  const float* Wq = (const float*)d_in[1];
  const float* Wk = (const float*)d_in[2];
  const float* Wv = (const float*)d_in[3];
  const float* Wo = (const float*)d_in[4];
  const int*   tp = (const int*)d_in[5];

  char* ws = (char*)d_ws;
  u16* Wt = (u16*)ws;
  u16* xb = (u16*)(ws + 33554432);
  u16* Qb = (u16*)(ws + 50331648);
  u16* Kb = (u16*)(ws + 67108864);
  u16* Vb = (u16*)(ws + 83886080);
  u16* Ob = (u16*)(ws + 100663296);

  conv_x_k<<<8192, 256, 0, stream>>>(x, xb);
  conv_w_k<<<dim3(64, 64, 4), 256, 0, stream>>>(Wq, Wk, Wv, Wo, Wt);
  gemm_k<<<dim3(8, 32, 3), 256, 0, stream>>>(xb, Wt, Qb, Kb, Vb, nullptr, tp, 0);
  attn_k<<<1024, 256, 0, stream>>>(Qb, Kb, Vb, Ob);
  gemm_k<<<dim3(8, 32, 1), 256, 0, stream>>>(Ob, Wt, nullptr, nullptr,
                                             nullptr, (float*)d_out, tp, 1);
}

// Round 5
// 388.215 us; speedup vs baseline: 1.0770x; 1.0770x over previous
//
#include <hip/hip_runtime.h>
#include <hip/hip_bf16.h>

#define S 2048
#define DM 2048
#define NH 16
#define DH 128

typedef __attribute__((ext_vector_type(8))) short short8;
typedef __attribute__((ext_vector_type(4))) float floatx4;
typedef unsigned short u16;
typedef unsigned int u32;

__device__ __forceinline__ u16 f2bf(float f) {
  union { float f; u32 u; } v; v.f = f;
  u32 r = v.u + 0x7fffu + ((v.u >> 16) & 1u);
  return (u16)(r >> 16);
}
// HW packed round-to-nearest-even f32x2 -> bf16x2 (v_cvt_pk_bf16_f32)
__device__ __forceinline__ u32 pack2(float lo, float hi) {
  float2 f; f.x = lo; f.y = hi;
  __hip_bfloat162 h = __float22bfloat162_rn(f);
  union { __hip_bfloat162 h; u32 u; } c; c.h = h;
  return c.u;
}

__device__ __forceinline__ floatx4 mfma16(short8 a, short8 b, floatx4 c) {
  return __builtin_amdgcn_mfma_f32_16x16x32_bf16(a, b, c, 0, 0, 0);
}

// async global -> LDS, 16B per lane. LDS dest = wave-uniform base + lane*16.
__device__ __forceinline__ void async_cp16(const u16* g, u16* l) {
  __builtin_amdgcn_global_load_lds(
      (const __attribute__((address_space(1))) void*)g,
      (__attribute__((address_space(3))) void*)l, 16, 0, 0);
}

// ---------- convert x (fp32 -> bf16), 4 elems/thread ----------
__global__ void conv_x_k(const float* __restrict__ x, u16* __restrict__ xb) {
  int gid = blockIdx.x * 256 + threadIdx.x;
  float4 v = ((const float4*)x)[gid];
  uint2 p; p.x = pack2(v.x, v.y); p.y = pack2(v.z, v.w);
  ((uint2*)xb)[gid] = p;
}

// ---------- transpose+convert weights: Wt[n*2048+k] = bf16(W[k*2048+n]) ----------
__global__ void conv_w_k(const float* __restrict__ W0, const float* __restrict__ W1,
                         const float* __restrict__ W2, const float* __restrict__ W3,
                         u16* __restrict__ out) {
  __shared__ float tile[32][33];
  const float* W = blockIdx.z == 0 ? W0 : blockIdx.z == 1 ? W1 : blockIdx.z == 2 ? W2 : W3;
  u16* O = out + (size_t)blockIdx.z * DM * DM;
  int tx = threadIdx.x & 31, ty = threadIdx.x >> 5;
  int k0 = blockIdx.y * 32, n0 = blockIdx.x * 32;
#pragma unroll
  for (int j = 0; j < 4; j++)
    tile[ty + j * 8][tx] = W[(size_t)(k0 + ty + j * 8) * DM + n0 + tx];
  __syncthreads();
#pragma unroll
  for (int j = 0; j < 4; j++)
    O[(size_t)(n0 + ty + j * 8) * DM + k0 + tx] = f2bf(tile[tx][ty + j * 8]);
}

// ---------- 256x256 bf16 MFMA GEMM (m201-geometry port) ----------
// 8 waves as 2M x 4N -> per-wave 128x64 (8 m-frags x 4 n-frags): 24
// ds_read_b128 vs 64 MFMA per K-tile per wave, AND 2 waves/SIMD so the two
// resident waves co-hide each other's LDS latency inside each phase (round-4
// lesson: 1 wave/SIMD exposes every stall; rounds 1-2 lesson: per-wave tile
// smaller than 128x64 makes the read leg longer than the MFMA leg).
// 4 phases/K-tile, each {ds_read quadrant -> bar -> lgkm0 -> 16 MFMA -> bar}:
//  ph0: a(m0-3)x2k + b(n0-1)x2k (12 rd), MFMA m0-3 x n0-1; stage A j0-3
//  ph1: b(n2-3)x2k (4 rd),              MFMA m0-3 x n2-3; stage B j0-3
//  ph2: a(m4-7)x2k (8 rd),              MFMA m4-7 x n0-1
//  ph3: no reads,                       MFMA m4-7 x n2-3; vmcnt(0); bar
// Staging for tile T+1 (8 loads/thread) is fully issued by end of ph1, so the
// ph3 wait has ~2.5 phases (>1200 cy) of slack over HBM/L2 latency.
// LDS 2x(32+32) KiB = 128 KiB double-buffered; swizzle: stored granule s of a
// row holds source granule s^(row&7); reads use (ks^(l16&7)) (involution,
// both-sides rule). 0 bank conflicts measured with this pattern in r0-r4.
#define BM 256
#define BN 256
#define BK 64

#define BARRIER __builtin_amdgcn_s_barrier()
#define SB __builtin_amdgcn_sched_barrier(0)
#define LGKM0 asm volatile("s_waitcnt lgkmcnt(0)" ::: "memory")

#define STG_A(q, j, koff) \
  async_cp16(pAg + (size_t)(j) * 64 * DM + (koff), &As[q][soff + (j) * 4096])
#define STG_B(q, j, koff) \
  async_cp16(pBg + (size_t)(j) * 64 * DM + (koff), &Bs[q][soff + (j) * 4096])

#define PH0(p, q, koff, PRE) { \
    a0k0 = *(const short8*)&As[p][awb + xk0]; \
    a0k1 = *(const short8*)&As[p][awb + xk1]; \
    a1k0 = *(const short8*)&As[p][awb + 1024 + xk0]; \
    a1k1 = *(const short8*)&As[p][awb + 1024 + xk1]; \
    a2k0 = *(const short8*)&As[p][awb + 2048 + xk0]; \
    a2k1 = *(const short8*)&As[p][awb + 2048 + xk1]; \
    a3k0 = *(const short8*)&As[p][awb + 3072 + xk0]; \
    a3k1 = *(const short8*)&As[p][awb + 3072 + xk1]; \
    b0k0 = *(const short8*)&Bs[p][bwb + xk0]; \
    b0k1 = *(const short8*)&Bs[p][bwb + xk1]; \
    b1k0 = *(const short8*)&Bs[p][bwb + 1024 + xk0]; \
    b1k1 = *(const short8*)&Bs[p][bwb + 1024 + xk1]; \
    if (PRE) { STG_A(q, 0, koff); STG_A(q, 1, koff); \
               STG_A(q, 2, koff); STG_A(q, 3, koff); } \
    BARRIER; LGKM0; SB; \
    __builtin_amdgcn_s_setprio(1); \
    acc[0][0] = mfma16(a0k0, b0k0, acc[0][0]); \
    acc[1][0] = mfma16(a1k0, b0k0, acc[1][0]); \
    acc[2][0] = mfma16(a2k0, b0k0, acc[2][0]); \
    acc[3][0] = mfma16(a3k0, b0k0, acc[3][0]); \
    acc[0][1] = mfma16(a0k0, b1k0, acc[0][1]); \
    acc[1][1] = mfma16(a1k0, b1k0, acc[1][1]); \
    acc[2][1] = mfma16(a2k0, b1k0, acc[2][1]); \
    acc[3][1] = mfma16(a3k0, b1k0, acc[3][1]); \
    acc[0][0] = mfma16(a0k1, b0k1, acc[0][0]); \
    acc[1][0] = mfma16(a1k1, b0k1, acc[1][0]); \
    acc[2][0] = mfma16(a2k1, b0k1, acc[2][0]); \
    acc[3][0] = mfma16(a3k1, b0k1, acc[3][0]); \
    acc[0][1] = mfma16(a0k1, b1k1, acc[0][1]); \
    acc[1][1] = mfma16(a1k1, b1k1, acc[1][1]); \
    acc[2][1] = mfma16(a2k1, b1k1, acc[2][1]); \
    acc[3][1] = mfma16(a3k1, b1k1, acc[3][1]); \
    __builtin_amdgcn_s_setprio(0); \
    BARRIER; }

#define PH1(p, q, koff, PRE) { \
    b2k0 = *(const short8*)&Bs[p][bwb + 2048 + xk0]; \
    b2k1 = *(const short8*)&Bs[p][bwb + 2048 + xk1]; \
    b3k0 = *(const short8*)&Bs[p][bwb + 3072 + xk0]; \
    b3k1 = *(const short8*)&Bs[p][bwb + 3072 + xk1]; \
    if (PRE) { STG_B(q, 0, koff); STG_B(q, 1, koff); \
               STG_B(q, 2, koff); STG_B(q, 3, koff); } \
    BARRIER; LGKM0; SB; \
    __builtin_amdgcn_s_setprio(1); \
    acc[0][2] = mfma16(a0k0, b2k0, acc[0][2]); \
    acc[1][2] = mfma16(a1k0, b2k0, acc[1][2]); \
    acc[2][2] = mfma16(a2k0, b2k0, acc[2][2]); \
    acc[3][2] = mfma16(a3k0, b2k0, acc[3][2]); \
    acc[0][3] = mfma16(a0k0, b3k0, acc[0][3]); \
    acc[1][3] = mfma16(a1k0, b3k0, acc[1][3]); \
    acc[2][3] = mfma16(a2k0, b3k0, acc[2][3]); \
    acc[3][3] = mfma16(a3k0, b3k0, acc[3][3]); \
    acc[0][2] = mfma16(a0k1, b2k1, acc[0][2]); \
    acc[1][2] = mfma16(a1k1, b2k1, acc[1][2]); \
    acc[2][2] = mfma16(a2k1, b2k1, acc[2][2]); \
    acc[3][2] = mfma16(a3k1, b2k1, acc[3][2]); \
    acc[0][3] = mfma16(a0k1, b3k1, acc[0][3]); \
    acc[1][3] = mfma16(a1k1, b3k1, acc[1][3]); \
    acc[2][3] = mfma16(a2k1, b3k1, acc[2][3]); \
    acc[3][3] = mfma16(a3k1, b3k1, acc[3][3]); \
    __builtin_amdgcn_s_setprio(0); \
    BARRIER; }

#define PH2(p) { \
    a0k0 = *(const short8*)&As[p][awb + 4096 + xk0]; \
    a0k1 = *(const short8*)&As[p][awb + 4096 + xk1]; \
    a1k0 = *(const short8*)&As[p][awb + 5120 + xk0]; \
    a1k1 = *(const short8*)&As[p][awb + 5120 + xk1]; \
    a2k0 = *(const short8*)&As[p][awb + 6144 + xk0]; \
    a2k1 = *(const short8*)&As[p][awb + 6144 + xk1]; \
    a3k0 = *(const short8*)&As[p][awb + 7168 + xk0]; \
    a3k1 = *(const short8*)&As[p][awb + 7168 + xk1]; \
    BARRIER; LGKM0; SB; \
    __builtin_amdgcn_s_setprio(1); \
    acc[4][0] = mfma16(a0k0, b0k0, acc[4][0]); \
    acc[5][0] = mfma16(a1k0, b0k0, acc[5][0]); \
    acc[6][0] = mfma16(a2k0, b0k0, acc[6][0]); \
    acc[7][0] = mfma16(a3k0, b0k0, acc[7][0]); \
    acc[4][1] = mfma16(a0k0, b1k0, acc[4][1]); \
    acc[5][1] = mfma16(a1k0, b1k0, acc[5][1]); \
    acc[6][1] = mfma16(a2k0, b1k0, acc[6][1]); \
    acc[7][1] = mfma16(a3k0, b1k0, acc[7][1]); \
    acc[4][0] = mfma16(a0k1, b0k1, acc[4][0]); \
    acc[5][0] = mfma16(a1k1, b0k1, acc[5][0]); \
    acc[6][0] = mfma16(a2k1, b0k1, acc[6][0]); \
    acc[7][0] = mfma16(a3k1, b0k1, acc[7][0]); \
    acc[4][1] = mfma16(a0k1, b1k1, acc[4][1]); \
    acc[5][1] = mfma16(a1k1, b1k1, acc[5][1]); \
    acc[6][1] = mfma16(a2k1, b1k1, acc[6][1]); \
    acc[7][1] = mfma16(a3k1, b1k1, acc[7][1]); \
    __builtin_amdgcn_s_setprio(0); \
    BARRIER; }

#define PH3(PRE) { \
    __builtin_amdgcn_s_setprio(1); \
    acc[4][2] = mfma16(a0k0, b2k0, acc[4][2]); \
    acc[5][2] = mfma16(a1k0, b2k0, acc[5][2]); \
    acc[6][2] = mfma16(a2k0, b2k0, acc[6][2]); \
    acc[7][2] = mfma16(a3k0, b2k0, acc[7][2]); \
    acc[4][3] = mfma16(a0k0, b3k0, acc[4][3]); \
    acc[5][3] = mfma16(a1k0, b3k0, acc[5][3]); \
    acc[6][3] = mfma16(a2k0, b3k0, acc[6][3]); \
    acc[7][3] = mfma16(a3k0, b3k0, acc[7][3]); \
    acc[4][2] = mfma16(a0k1, b2k1, acc[4][2]); \
    acc[5][2] = mfma16(a1k1, b2k1, acc[5][2]); \
    acc[6][2] = mfma16(a2k1, b2k1, acc[6][2]); \
    acc[7][2] = mfma16(a3k1, b2k1, acc[7][2]); \
    acc[4][3] = mfma16(a0k1, b3k1, acc[4][3]); \
    acc[5][3] = mfma16(a1k1, b3k1, acc[5][3]); \
    acc[6][3] = mfma16(a2k1, b3k1, acc[6][3]); \
    acc[7][3] = mfma16(a3k1, b3k1, acc[7][3]); \
    __builtin_amdgcn_s_setprio(0); SB; \
    if (PRE) { asm volatile("s_waitcnt vmcnt(0)" ::: "memory"); BARRIER; SB; } }

#define TILE(p, q, koff, PRE) \
    PH0(p, q, koff, PRE) PH1(p, q, koff, PRE) PH2(p) PH3(PRE)

__global__ __launch_bounds__(512, 2)
void gemm_k(const u16* __restrict__ A, const u16* __restrict__ Wt,
            u16* __restrict__ oQ, u16* __restrict__ oK, u16* __restrict__ oV,
            float* __restrict__ oO, const int* __restrict__ tp, int opmode)
{
  __shared__ u16 As[2][BM * BK];   // 2 x 32 KiB
  __shared__ u16 Bs[2][BN * BK];   // 2 x 32 KiB -> 128 KiB total
  const int t = threadIdx.x;
  const int w = t >> 6, lane = t & 63;
  const int l16 = lane & 15, quad = lane >> 4;
  const int wr = w >> 2, wc = w & 3;     // 2M x 4N waves, 128x64 each
  const int m0 = blockIdx.y * BM, n0 = blockIdx.x * BN;
  const u16* Bt = Wt + (size_t)(opmode == 1 ? 3 : blockIdx.z) * DM * DM;

  // staging: unit u = t + j*512 -> row u>>3 = (t>>3)+j*64, stored granule u&7
  // holds source granule (u&7)^(row&7); both are j-invariant.
  const int srow = t >> 3;
  const int sc = ((t & 7) ^ (srow & 7)) * 8;
  const u16* pAg = A + (size_t)(m0 + srow) * DM + sc;
  const u16* pBg = Bt + (size_t)(n0 + srow) * DM + sc;
  const int soff = t * 8;

  // fragment read offsets (u16 units); row&7 == l16&7 (row bases mult. of 16)
  const int awb = (wr * 128 + l16) * 64;
  const int bwb = (wc * 64 + l16) * 64;
  const int xk0 = ((quad) ^ (l16 & 7)) << 3;
  const int xk1 = ((4 + quad) ^ (l16 & 7)) << 3;

  floatx4 acc[8][4] = {};
  short8 a0k0, a0k1, a1k0, a1k1, a2k0, a2k1, a3k0, a3k1;
  short8 b0k0, b0k1, b1k0, b1k1, b2k0, b2k1, b3k0, b3k1;

  // ---- prologue: tile 0 -> buf0 (8 loads/thread), full wait once
#pragma unroll
  for (int j = 0; j < 4; j++) STG_A(0, j, 0);
#pragma unroll
  for (int j = 0; j < 4; j++) STG_B(0, j, 0);
  SB;
  asm volatile("s_waitcnt vmcnt(0)" ::: "memory");
  BARRIER; SB;

  for (int it = 0; it < 16; ++it) {
    const int kA = (2 * it + 1) * 64;    // stage tile 2it+1 -> buf1
    const int kB = (2 * it + 2) * 64;    // stage tile 2it+2 -> buf0
    TILE(0, 1, kA, 1)                    // compute tile 2it   (buf0)
    TILE(1, 0, kB, it < 15)              // compute tile 2it+1 (buf1)
  }

  // ---- epilogue: per-wave 128x64; m = m0+wr*128+mi*16+quad*4+r, n = n0+wc*64+ni*16+l16
  const int mode = (opmode == 1) ? 3 : ((int)blockIdx.z == 2 ? 2 : 0);
  const int mwb = m0 + wr * 128;
  const int nwb = n0 + wc * 64;
  if (mode == 3) {
#pragma unroll
    for (int mi = 0; mi < 8; mi++) {
      int m = mwb + mi * 16 + quad * 4;
#pragma unroll
      for (int ni = 0; ni < 4; ni++) {
        int n = nwb + ni * 16 + l16;
#pragma unroll
        for (int r = 0; r < 4; r++)
          oO[(size_t)(m + r) * DM + n] = acc[mi][ni][r];
      }
    }
  } else if (mode == 2) {
#pragma unroll
    for (int mi = 0; mi < 8; mi++) {
      int m = mwb + mi * 16 + quad * 4;
      int b = m >> 11, s = m & (S - 1);
#pragma unroll
      for (int ni = 0; ni < 4; ni++) {
        int f = nwb + ni * 16 + l16;
        int h = f >> 7, dh = f & (DH - 1);
        uint2 pk; pk.x = pack2(acc[mi][ni][0], acc[mi][ni][1]);
        pk.y = pack2(acc[mi][ni][2], acc[mi][ni][3]);
        *(uint2*)&oV[((size_t)(b * NH + h) * DH + dh) * S + s] = pk;
      }
    }
  } else {
    // RoPE fused; for Q (z==0) also fold 1/sqrt(dk)*log2(e) into the value
    u16* Out = ((int)blockIdx.z == 0) ? oQ : oK;
    const float qs = ((int)blockIdx.z == 0) ? 0.12752780f : 1.0f;
#pragma unroll
    for (int mi = 0; mi < 8; mi++) {
#pragma unroll
      for (int r = 0; r < 4; r++) {
        int m = mwb + mi * 16 + quad * 4 + r;
        int b = m >> 11, s = m & (S - 1);
        int ps = tp[s];
#pragma unroll
        for (int ni = 0; ni < 4; ni++) {
          int f = nwb + ni * 16 + l16;
          int h = f >> 7, dh = f & (DH - 1);
          float own = acc[mi][ni][r];
          float oth = __shfl_xor(own, 1, 64);
          float fr = __expf((float)(dh & ~1) * (-9.210340371976184f / 128.0f));
          float ang = (float)ps * fr;
          float sn, cs; __sincosf(ang, &sn, &cs);
          float res = (dh & 1) ? (oth * sn + own * cs) : (own * cs - oth * sn);
          Out[((size_t)(b * NH + h) * S + s) * DH + dh] = f2bf(res * qs);
        }
      }
    }
  }
}

// ---------- causal flash attention v7: 16 q/wave, fixed-base softmax, 40KB LDS ----------
// P is unpadded (16x64) with 16B-granule XOR swizzle -> Ks+Vs+P = 40960 B exactly,
// 4 blocks/CU at __launch_bounds__(256,4). Fixed-base softmax as v6.
__global__ __launch_bounds__(256, 4)
void attn_k(const u16* __restrict__ Q, const u16* __restrict__ K,
            const u16* __restrict__ Vt, u16* __restrict__ O)
{
  __shared__ u16 Ks[64 * 128];   // key-major, swizzle: unit r*16 + (c ^ (r&15))
  __shared__ u16 Vs[128 * 64];   // dh-major,  swizzle: unit r*8  + (c ^ (r&7))
  __shared__ u16 P[4][16 * 64];  // per-wave 16 q x 64 keys, 16B-XOR-swizzled
  const int t = threadIdx.x, w = t >> 6, lane = t & 63;
  const int l16 = lane & 15, quad = lane >> 4;
  const int task = blockIdx.x;
  const int bh = task & 31, b = bh >> 4, h = bh & 15;
  const int g = 31 - (task >> 5);        // big groups dispatch first (LPT)
  const int qg = g * 64;
  const int qt = qg + w * 16;
  const u16* Qb = Q + (size_t)bh * S * DH;
  const u16* Kb = K + (size_t)bh * S * DH;
  const u16* Vb = Vt + (size_t)bh * DH * S;
  u16* Pw = P[w];
  const int pxor = l16 & 7;

  const u16* pK[4]; u16* lK[4];
  const u16* pV[4]; u16* lV[4];
#pragma unroll
  for (int j = 0; j < 4; j++) {
    int kr = w * 16 + j * 4 + (lane >> 4);
    int ks = lane & 15;
    int kc = ks ^ (kr & 15);
    pK[j] = Kb + (size_t)kr * DH + kc * 8;
    lK[j] = &Ks[kr * 128 + ks * 8];
    int vr = w * 32 + j * 8 + (lane >> 3);
    int vs = lane & 7;
    int vc = vs ^ (vr & 7);
    pV[j] = Vb + (size_t)vr * S + vc * 8;
    lV[j] = &Vs[vr * 64 + vs * 8];
  }

  short8 aq[4];
#pragma unroll
  for (int kc = 0; kc < 4; kc++)
    aq[kc] = *(const short8*)&Qb[(size_t)(qt + l16) * DH + kc * 32 + quad * 8];

  floatx4 o[8] = {};
  float lsum = 0.0f;                 // per-lane partial: keys in own quad-subset
  const int kend = qg + 64;

  for (int k0 = 0; k0 < kend; k0 += 64) {
#pragma unroll
    for (int j = 0; j < 4; j++) async_cp16(pK[j] + (size_t)k0 * DH, lK[j]);
#pragma unroll
    for (int j = 0; j < 4; j++) async_cp16(pV[j] + k0, lV[j]);
    __syncthreads();

    // ---- S^T = K·Q^T : sc[hh] row = key k0+hh*16+quad*4+r, col = q = l16
    floatx4 sc[4] = {};
#pragma unroll
    for (int hh = 0; hh < 4; hh++) {
      int row = hh * 16 + l16;
#pragma unroll
      for (int kc = 0; kc < 4; kc++) {
        short8 kf = *(short8*)&Ks[row * 128 + (((kc * 4 + quad) ^ l16) << 3)];
        sc[hh] = mfma16(kf, aq[kc], sc[hh]);
      }
    }
    // ---- causal mask (only the diagonal-overlapping tile)
    if (k0 + 64 > qt) {
#pragma unroll
      for (int hh = 0; hh < 4; hh++)
#pragma unroll
        for (int r = 0; r < 4; r++) {
          int j = k0 + hh * 16 + quad * 4 + r;
          if (j > qt + l16) sc[hh][r] = -3.0e38f;
        }
    }
    // ---- direct exp2 softmax numerator; per-lane l accumulation
#pragma unroll
    for (int hh = 0; hh < 4; hh++) {
      float e0 = __builtin_amdgcn_exp2f(fminf(sc[hh][0], 44.0f));
      float e1 = __builtin_amdgcn_exp2f(fminf(sc[hh][1], 44.0f));
      float e2 = __builtin_amdgcn_exp2f(fminf(sc[hh][2], 44.0f));
      float e3 = __builtin_amdgcn_exp2f(fminf(sc[hh][3], 44.0f));
      lsum += (e0 + e1) + (e2 + e3);
      uint2 pk; pk.x = pack2(e0, e1); pk.y = pack2(e2, e3);
      // write keys hh*16+quad*4..+3 of row q=l16: 16B-unit u = 2hh + quad/2,
      // swizzled u^pxor, 8B half (quad&1)
      int su = (2 * hh + (quad >> 1)) ^ pxor;
      *(uint2*)&Pw[l16 * 64 + su * 8 + (quad & 1) * 4] = pk;
    }
    asm volatile("s_waitcnt lgkmcnt(0)" ::: "memory");
    // ---- O^T += V^T · P^T
#pragma unroll
    for (int c = 0; c < 2; c++) {
      // read keys c*32+quad*8..+7 of row l16: 16B-unit u = 4c+quad, swizzled
      short8 pf = *(short8*)&Pw[l16 * 64 + (((4 * c + quad) ^ pxor) << 3)];
#pragma unroll
      for (int t8 = 0; t8 < 8; t8++) {
        int row = t8 * 16 + l16;
        short8 av = *(short8*)&Vs[row * 64 + (((c * 4 + quad) ^ (l16 & 7)) << 3)];
        o[t8] = mfma16(av, pf, o[t8]);
      }
    }
    __syncthreads();
  }

  // ---- epilogue: reduce l across quads ONCE, then scale and store
  float l = lsum + __shfl_xor(lsum, 16, 64);
  l += __shfl_xor(l, 32, 64);
  float inv = __builtin_amdgcn_rcpf(l);
#pragma unroll
  for (int t8 = 0; t8 < 8; t8++) {
    uint2 pa;
    pa.x = pack2(o[t8][0] * inv, o[t8][1] * inv);
    pa.y = pack2(o[t8][2] * inv, o[t8][3] * inv);
    *(uint2*)&O[((size_t)(b * S + qt + l16)) * DM + h * DH + t8 * 16 + quad * 4] = pa;
  }
}

extern "C" void kernel_launch(void* const* d_in, const int* in_sizes, int n_in,
                              void* d_out, int out_size, void* d_ws, size_t ws_size,
                              hipStream_t stream) {
  const float* x  = (const float*)d_in[0];
  const float* Wq = (const float*)d_in[1];
  const float* Wk = (const float*)d_in[2];
  const float* Wv = (const float*)d_in[3];
  const float* Wo = (const float*)d_in[4];
  const int*   tp = (const int*)d_in[5];

  char* ws = (char*)d_ws;
  u16* Wt = (u16*)ws;
  u16* xb = (u16*)(ws + 33554432);
  u16* Qb = (u16*)(ws + 50331648);
  u16* Kb = (u16*)(ws + 67108864);
  u16* Vb = (u16*)(ws + 83886080);
  u16* Ob = (u16*)(ws + 100663296);

  conv_x_k<<<8192, 256, 0, stream>>>(x, xb);
  conv_w_k<<<dim3(64, 64, 4), 256, 0, stream>>>(Wq, Wk, Wv, Wo, Wt);
  gemm_k<<<dim3(8, 16, 3), 512, 0, stream>>>(xb, Wt, Qb, Kb, Vb, nullptr, tp, 0);
  attn_k<<<1024, 256, 0, stream>>>(Qb, Kb, Vb, Ob);
  gemm_k<<<dim3(8, 16, 1), 512, 0, stream>>>(Ob, Wt, nullptr, nullptr,
                                             nullptr, (float*)d_out, tp, 1);
}

// Round 6
// 378.340 us; speedup vs baseline: 1.1051x; 1.0261x over previous
//
#include <hip/hip_runtime.h>
#include <hip/hip_bf16.h>

#define S 2048
#define DM 2048
#define NH 16
#define DH 128

typedef __attribute__((ext_vector_type(8))) short short8;
typedef __attribute__((ext_vector_type(4))) float floatx4;
typedef unsigned short u16;
typedef unsigned int u32;

__device__ __forceinline__ u16 f2bf(float f) {
  union { float f; u32 u; } v; v.f = f;
  u32 r = v.u + 0x7fffu + ((v.u >> 16) & 1u);
  return (u16)(r >> 16);
}
// HW packed round-to-nearest-even f32x2 -> bf16x2 (v_cvt_pk_bf16_f32)
__device__ __forceinline__ u32 pack2(float lo, float hi) {
  float2 f; f.x = lo; f.y = hi;
  __hip_bfloat162 h = __float22bfloat162_rn(f);
  union { __hip_bfloat162 h; u32 u; } c; c.h = h;
  return c.u;
}

__device__ __forceinline__ floatx4 mfma16(short8 a, short8 b, floatx4 c) {
  return __builtin_amdgcn_mfma_f32_16x16x32_bf16(a, b, c, 0, 0, 0);
}

// async global -> LDS, 16B per lane. LDS dest = wave-uniform base + lane*16.
__device__ __forceinline__ void async_cp16(const u16* g, u16* l) {
  __builtin_amdgcn_global_load_lds(
      (const __attribute__((address_space(1))) void*)g,
      (__attribute__((address_space(3))) void*)l, 16, 0, 0);
}

// ---------- convert x (fp32 -> bf16), 4 elems/thread ----------
__global__ void conv_x_k(const float* __restrict__ x, u16* __restrict__ xb) {
  int gid = blockIdx.x * 256 + threadIdx.x;
  float4 v = ((const float4*)x)[gid];
  uint2 p; p.x = pack2(v.x, v.y); p.y = pack2(v.z, v.w);
  ((uint2*)xb)[gid] = p;
}

// ---------- transpose+convert weights: Wt[n*2048+k] = bf16(W[k*2048+n]) ----------
__global__ void conv_w_k(const float* __restrict__ W0, const float* __restrict__ W1,
                         const float* __restrict__ W2, const float* __restrict__ W3,
                         u16* __restrict__ out) {
  __shared__ float tile[32][33];
  const float* W = blockIdx.z == 0 ? W0 : blockIdx.z == 1 ? W1 : blockIdx.z == 2 ? W2 : W3;
  u16* O = out + (size_t)blockIdx.z * DM * DM;
  int tx = threadIdx.x & 31, ty = threadIdx.x >> 5;
  int k0 = blockIdx.y * 32, n0 = blockIdx.x * 32;
#pragma unroll
  for (int j = 0; j < 4; j++)
    tile[ty + j * 8][tx] = W[(size_t)(k0 + ty + j * 8) * DM + n0 + tx];
  __syncthreads();
#pragma unroll
  for (int j = 0; j < 4; j++)
    O[(size_t)(n0 + ty + j * 8) * DM + k0 + tx] = f2bf(tile[tx][ty + j * 8]);
}

// ---------- 256x256 bf16 MFMA GEMM for QKV (best measured: 138 us) ----------
// 8 waves as 2M x 4N -> per-wave 128x64; 4 phases/K-tile; double-buffered
// 128 KiB LDS; staging issued in ph0/ph1 for tile T+1, vmcnt(0) at ph3.
// Measured r5: MfmaUtil 30.5%, 0 bank conflicts. Legs serialize (sum not max)
// -- structural; kept as best-known while O-proj moves to its own kernel.
#define BM 256
#define BN 256
#define BK 64

#define BARRIER __builtin_amdgcn_s_barrier()
#define SB __builtin_amdgcn_sched_barrier(0)
#define LGKM0 asm volatile("s_waitcnt lgkmcnt(0)" ::: "memory")

#define STG_A(q, j, koff) \
  async_cp16(pAg + (size_t)(j) * 64 * DM + (koff), &As[q][soff + (j) * 4096])
#define STG_B(q, j, koff) \
  async_cp16(pBg + (size_t)(j) * 64 * DM + (koff), &Bs[q][soff + (j) * 4096])

#define PH0(p, q, koff, PRE) { \
    a0k0 = *(const short8*)&As[p][awb + xk0]; \
    a0k1 = *(const short8*)&As[p][awb + xk1]; \
    a1k0 = *(const short8*)&As[p][awb + 1024 + xk0]; \
    a1k1 = *(const short8*)&As[p][awb + 1024 + xk1]; \
    a2k0 = *(const short8*)&As[p][awb + 2048 + xk0]; \
    a2k1 = *(const short8*)&As[p][awb + 2048 + xk1]; \
    a3k0 = *(const short8*)&As[p][awb + 3072 + xk0]; \
    a3k1 = *(const short8*)&As[p][awb + 3072 + xk1]; \
    b0k0 = *(const short8*)&Bs[p][bwb + xk0]; \
    b0k1 = *(const short8*)&Bs[p][bwb + xk1]; \
    b1k0 = *(const short8*)&Bs[p][bwb + 1024 + xk0]; \
    b1k1 = *(const short8*)&Bs[p][bwb + 1024 + xk1]; \
    if (PRE) { STG_A(q, 0, koff); STG_A(q, 1, koff); \
               STG_A(q, 2, koff); STG_A(q, 3, koff); } \
    BARRIER; LGKM0; SB; \
    __builtin_amdgcn_s_setprio(1); \
    acc[0][0] = mfma16(a0k0, b0k0, acc[0][0]); \
    acc[1][0] = mfma16(a1k0, b0k0, acc[1][0]); \
    acc[2][0] = mfma16(a2k0, b0k0, acc[2][0]); \
    acc[3][0] = mfma16(a3k0, b0k0, acc[3][0]); \
    acc[0][1] = mfma16(a0k0, b1k0, acc[0][1]); \
    acc[1][1] = mfma16(a1k0, b1k0, acc[1][1]); \
    acc[2][1] = mfma16(a2k0, b1k0, acc[2][1]); \
    acc[3][1] = mfma16(a3k0, b1k0, acc[3][1]); \
    acc[0][0] = mfma16(a0k1, b0k1, acc[0][0]); \
    acc[1][0] = mfma16(a1k1, b0k1, acc[1][0]); \
    acc[2][0] = mfma16(a2k1, b0k1, acc[2][0]); \
    acc[3][0] = mfma16(a3k1, b0k1, acc[3][0]); \
    acc[0][1] = mfma16(a0k1, b1k1, acc[0][1]); \
    acc[1][1] = mfma16(a1k1, b1k1, acc[1][1]); \
    acc[2][1] = mfma16(a2k1, b1k1, acc[2][1]); \
    acc[3][1] = mfma16(a3k1, b1k1, acc[3][1]); \
    __builtin_amdgcn_s_setprio(0); \
    BARRIER; }

#define PH1(p, q, koff, PRE) { \
    b2k0 = *(const short8*)&Bs[p][bwb + 2048 + xk0]; \
    b2k1 = *(const short8*)&Bs[p][bwb + 2048 + xk1]; \
    b3k0 = *(const short8*)&Bs[p][bwb + 3072 + xk0]; \
    b3k1 = *(const short8*)&Bs[p][bwb + 3072 + xk1]; \
    if (PRE) { STG_B(q, 0, koff); STG_B(q, 1, koff); \
               STG_B(q, 2, koff); STG_B(q, 3, koff); } \
    BARRIER; LGKM0; SB; \
    __builtin_amdgcn_s_setprio(1); \
    acc[0][2] = mfma16(a0k0, b2k0, acc[0][2]); \
    acc[1][2] = mfma16(a1k0, b2k0, acc[1][2]); \
    acc[2][2] = mfma16(a2k0, b2k0, acc[2][2]); \
    acc[3][2] = mfma16(a3k0, b2k0, acc[3][2]); \
    acc[0][3] = mfma16(a0k0, b3k0, acc[0][3]); \
    acc[1][3] = mfma16(a1k0, b3k0, acc[1][3]); \
    acc[2][3] = mfma16(a2k0, b3k0, acc[2][3]); \
    acc[3][3] = mfma16(a3k0, b3k0, acc[3][3]); \
    acc[0][2] = mfma16(a0k1, b2k1, acc[0][2]); \
    acc[1][2] = mfma16(a1k1, b2k1, acc[1][2]); \
    acc[2][2] = mfma16(a2k1, b2k1, acc[2][2]); \
    acc[3][2] = mfma16(a3k1, b2k1, acc[3][2]); \
    acc[0][3] = mfma16(a0k1, b3k1, acc[0][3]); \
    acc[1][3] = mfma16(a1k1, b3k1, acc[1][3]); \
    acc[2][3] = mfma16(a2k1, b3k1, acc[2][3]); \
    acc[3][3] = mfma16(a3k1, b3k1, acc[3][3]); \
    __builtin_amdgcn_s_setprio(0); \
    BARRIER; }

#define PH2(p) { \
    a0k0 = *(const short8*)&As[p][awb + 4096 + xk0]; \
    a0k1 = *(const short8*)&As[p][awb + 4096 + xk1]; \
    a1k0 = *(const short8*)&As[p][awb + 5120 + xk0]; \
    a1k1 = *(const short8*)&As[p][awb + 5120 + xk1]; \
    a2k0 = *(const short8*)&As[p][awb + 6144 + xk0]; \
    a2k1 = *(const short8*)&As[p][awb + 6144 + xk1]; \
    a3k0 = *(const short8*)&As[p][awb + 7168 + xk0]; \
    a3k1 = *(const short8*)&As[p][awb + 7168 + xk1]; \
    BARRIER; LGKM0; SB; \
    __builtin_amdgcn_s_setprio(1); \
    acc[4][0] = mfma16(a0k0, b0k0, acc[4][0]); \
    acc[5][0] = mfma16(a1k0, b0k0, acc[5][0]); \
    acc[6][0] = mfma16(a2k0, b0k0, acc[6][0]); \
    acc[7][0] = mfma16(a3k0, b0k0, acc[7][0]); \
    acc[4][1] = mfma16(a0k0, b1k0, acc[4][1]); \
    acc[5][1] = mfma16(a1k0, b1k0, acc[5][1]); \
    acc[6][1] = mfma16(a2k0, b1k0, acc[6][1]); \
    acc[7][1] = mfma16(a3k0, b1k0, acc[7][1]); \
    acc[4][0] = mfma16(a0k1, b0k1, acc[4][0]); \
    acc[5][0] = mfma16(a1k1, b0k1, acc[5][0]); \
    acc[6][0] = mfma16(a2k1, b0k1, acc[6][0]); \
    acc[7][0] = mfma16(a3k1, b0k1, acc[7][0]); \
    acc[4][1] = mfma16(a0k1, b1k1, acc[4][1]); \
    acc[5][1] = mfma16(a1k1, b1k1, acc[5][1]); \
    acc[6][1] = mfma16(a2k1, b1k1, acc[6][1]); \
    acc[7][1] = mfma16(a3k1, b1k1, acc[7][1]); \
    __builtin_amdgcn_s_setprio(0); \
    BARRIER; }

#define PH3(PRE) { \
    __builtin_amdgcn_s_setprio(1); \
    acc[4][2] = mfma16(a0k0, b2k0, acc[4][2]); \
    acc[5][2] = mfma16(a1k0, b2k0, acc[5][2]); \
    acc[6][2] = mfma16(a2k0, b2k0, acc[6][2]); \
    acc[7][2] = mfma16(a3k0, b2k0, acc[7][2]); \
    acc[4][3] = mfma16(a0k0, b3k0, acc[4][3]); \
    acc[5][3] = mfma16(a1k0, b3k0, acc[5][3]); \
    acc[6][3] = mfma16(a2k0, b3k0, acc[6][3]); \
    acc[7][3] = mfma16(a3k0, b3k0, acc[7][3]); \
    acc[4][2] = mfma16(a0k1, b2k1, acc[4][2]); \
    acc[5][2] = mfma16(a1k1, b2k1, acc[5][2]); \
    acc[6][2] = mfma16(a2k1, b2k1, acc[6][2]); \
    acc[7][2] = mfma16(a3k1, b2k1, acc[7][2]); \
    acc[4][3] = mfma16(a0k1, b3k1, acc[4][3]); \
    acc[5][3] = mfma16(a1k1, b3k1, acc[5][3]); \
    acc[6][3] = mfma16(a2k1, b3k1, acc[6][3]); \
    acc[7][3] = mfma16(a3k1, b3k1, acc[7][3]); \
    __builtin_amdgcn_s_setprio(0); SB; \
    if (PRE) { asm volatile("s_waitcnt vmcnt(0)" ::: "memory"); BARRIER; SB; } }

#define TILE(p, q, koff, PRE) \
    PH0(p, q, koff, PRE) PH1(p, q, koff, PRE) PH2(p) PH3(PRE)

__global__ __launch_bounds__(512, 2)
void gemm_k(const u16* __restrict__ A, const u16* __restrict__ Wt,
            u16* __restrict__ oQ, u16* __restrict__ oK, u16* __restrict__ oV,
            const int* __restrict__ tp)
{
  __shared__ u16 As[2][BM * BK];   // 2 x 32 KiB
  __shared__ u16 Bs[2][BN * BK];   // 2 x 32 KiB -> 128 KiB total
  const int t = threadIdx.x;
  const int w = t >> 6, lane = t & 63;
  const int l16 = lane & 15, quad = lane >> 4;
  const int wr = w >> 2, wc = w & 3;     // 2M x 4N waves, 128x64 each
  const int m0 = blockIdx.y * BM, n0 = blockIdx.x * BN;
  const u16* Bt = Wt + (size_t)blockIdx.z * DM * DM;

  // staging: unit u = t + j*512 -> row u>>3 = (t>>3)+j*64, stored granule u&7
  // holds source granule (u&7)^(row&7); both are j-invariant.
  const int srow = t >> 3;
  const int sc = ((t & 7) ^ (srow & 7)) * 8;
  const u16* pAg = A + (size_t)(m0 + srow) * DM + sc;
  const u16* pBg = Bt + (size_t)(n0 + srow) * DM + sc;
  const int soff = t * 8;

  // fragment read offsets (u16 units); row&7 == l16&7 (row bases mult. of 16)
  const int awb = (wr * 128 + l16) * 64;
  const int bwb = (wc * 64 + l16) * 64;
  const int xk0 = ((quad) ^ (l16 & 7)) << 3;
  const int xk1 = ((4 + quad) ^ (l16 & 7)) << 3;

  floatx4 acc[8][4] = {};
  short8 a0k0, a0k1, a1k0, a1k1, a2k0, a2k1, a3k0, a3k1;
  short8 b0k0, b0k1, b1k0, b1k1, b2k0, b2k1, b3k0, b3k1;

  // ---- prologue: tile 0 -> buf0 (8 loads/thread), full wait once
#pragma unroll
  for (int j = 0; j < 4; j++) STG_A(0, j, 0);
#pragma unroll
  for (int j = 0; j < 4; j++) STG_B(0, j, 0);
  SB;
  asm volatile("s_waitcnt vmcnt(0)" ::: "memory");
  BARRIER; SB;

  for (int it = 0; it < 16; ++it) {
    const int kA = (2 * it + 1) * 64;    // stage tile 2it+1 -> buf1
    const int kB = (2 * it + 2) * 64;    // stage tile 2it+2 -> buf0
    TILE(0, 1, kA, 1)                    // compute tile 2it   (buf0)
    TILE(1, 0, kB, it < 15)              // compute tile 2it+1 (buf1)
  }

  // ---- epilogue: per-wave 128x64; m = m0+wr*128+mi*16+quad*4+r, n = n0+wc*64+ni*16+l16
  const int mwb = m0 + wr * 128;
  const int nwb = n0 + wc * 64;
  if ((int)blockIdx.z == 2) {
#pragma unroll
    for (int mi = 0; mi < 8; mi++) {
      int m = mwb + mi * 16 + quad * 4;
      int b = m >> 11, s = m & (S - 1);
#pragma unroll
      for (int ni = 0; ni < 4; ni++) {
        int f = nwb + ni * 16 + l16;
        int h = f >> 7, dh = f & (DH - 1);
        uint2 pk; pk.x = pack2(acc[mi][ni][0], acc[mi][ni][1]);
        pk.y = pack2(acc[mi][ni][2], acc[mi][ni][3]);
        *(uint2*)&oV[((size_t)(b * NH + h) * DH + dh) * S + s] = pk;
      }
    }
  } else {
    // RoPE fused; for Q (z==0) also fold 1/sqrt(dk)*log2(e) into the value
    u16* Out = ((int)blockIdx.z == 0) ? oQ : oK;
    const float qs = ((int)blockIdx.z == 0) ? 0.12752780f : 1.0f;
#pragma unroll
    for (int mi = 0; mi < 8; mi++) {
#pragma unroll
      for (int r = 0; r < 4; r++) {
        int m = mwb + mi * 16 + quad * 4 + r;
        int b = m >> 11, s = m & (S - 1);
        int ps = tp[s];
#pragma unroll
        for (int ni = 0; ni < 4; ni++) {
          int f = nwb + ni * 16 + l16;
          int h = f >> 7, dh = f & (DH - 1);
          float own = acc[mi][ni][r];
          float oth = __shfl_xor(own, 1, 64);
          float fr = __expf((float)(dh & ~1) * (-9.210340371976184f / 128.0f));
          float ang = (float)ps * fr;
          float sn, cs; __sincosf(ang, &sn, &cs);
          float res = (dh & 1) ? (oth * sn + own * cs) : (own * cs - oth * sn);
          Out[((size_t)(b * NH + h) * S + s) * DH + dh] = f2bf(res * qs);
        }
      }
    }
  }
}

// ---------- O-projection: 128x128 bf16 MFMA GEMM, 4 blocks/CU (round-0 config) ----------
// Grid 16x32 = 512 blocks -> 2 full rounds at 4 blocks/CU (no idle-CU tail;
// r5's 256^2 O-proj left half the machine idle: 69 us vs 48 us here).
__global__ __launch_bounds__(256, 4)
void oproj_k(const u16* __restrict__ A, const u16* __restrict__ Wt,
             float* __restrict__ oO)
{
  __shared__ u16 As2[128 * 32];
  __shared__ u16 Bs2[128 * 32];
  const int t = threadIdx.x;
  const int w = t >> 6, lane = t & 63;
  const int l16 = lane & 15, quad = lane >> 4;
  const int m0 = blockIdx.y * 128, n0 = blockIdx.x * 128;
  const int wm = (w >> 1) * 64, wn = (w & 1) * 64;
  const u16* Bt = Wt + (size_t)3 * DM * DM;

  const u16* pA[2]; const u16* pB[2]; u16* lA[2]; u16* lB[2];
#pragma unroll
  for (int i = 0; i < 2; i++) {
    int unit = i * 256 + t;
    int row = unit >> 2, s = unit & 3;
    int c = s ^ ((row >> 1) & 3);
    pA[i] = A + (size_t)(m0 + row) * DM + c * 8;
    pB[i] = Bt + (size_t)(n0 + row) * DM + c * 8;
    lA[i] = &As2[unit * 8];
    lB[i] = &Bs2[unit * 8];
  }

  floatx4 acc[4][4] = {};

  for (int k0 = 0; k0 < DM; k0 += 32) {
#pragma unroll
    for (int i = 0; i < 2; i++) {
      async_cp16(pA[i] + k0, lA[i]);
      async_cp16(pB[i] + k0, lB[i]);
    }
    __syncthreads();
    short8 af[4], bfr[4];
#pragma unroll
    for (int i = 0; i < 4; i++) {
      int row = wm + i * 16 + l16;
      af[i] = *(short8*)&As2[(row * 4 + (quad ^ ((row >> 1) & 3))) * 8];
    }
#pragma unroll
    for (int i = 0; i < 4; i++) {
      int row = wn + i * 16 + l16;
      bfr[i] = *(short8*)&Bs2[(row * 4 + (quad ^ ((row >> 1) & 3))) * 8];
    }
#pragma unroll
    for (int mi = 0; mi < 4; mi++)
#pragma unroll
      for (int ni = 0; ni < 4; ni++)
        acc[mi][ni] = mfma16(af[mi], bfr[ni], acc[mi][ni]);
    __syncthreads();
  }

#pragma unroll
  for (int mi = 0; mi < 4; mi++) {
    int m = m0 + wm + mi * 16 + quad * 4;
#pragma unroll
    for (int ni = 0; ni < 4; ni++) {
      int n = n0 + wn + ni * 16 + l16;
#pragma unroll
      for (int r = 0; r < 4; r++)
        oO[(size_t)(m + r) * DM + n] = acc[mi][ni][r];
    }
  }
}

// ---------- causal flash attention v7 + T5 setprio: 16 q/wave, 40KB LDS ----------
// P is unpadded (16x64) with 16B-granule XOR swizzle -> Ks+Vs+P = 40960 B exactly,
// 4 blocks/CU at __launch_bounds__(256,4). setprio(1) around QK and PV MFMA
// clusters (T5: +4-7% measured on attn with independent blocks, m191).
__global__ __launch_bounds__(256, 4)
void attn_k(const u16* __restrict__ Q, const u16* __restrict__ K,
            const u16* __restrict__ Vt, u16* __restrict__ O)
{
  __shared__ u16 Ks[64 * 128];   // key-major, swizzle: unit r*16 + (c ^ (r&15))
  __shared__ u16 Vs[128 * 64];   // dh-major,  swizzle: unit r*8  + (c ^ (r&7))
  __shared__ u16 P[4][16 * 64];  // per-wave 16 q x 64 keys, 16B-XOR-swizzled
  const int t = threadIdx.x, w = t >> 6, lane = t & 63;
  const int l16 = lane & 15, quad = lane >> 4;
  const int task = blockIdx.x;
  const int bh = task & 31, b = bh >> 4, h = bh & 15;
  const int g = 31 - (task >> 5);        // big groups dispatch first (LPT)
  const int qg = g * 64;
  const int qt = qg + w * 16;
  const u16* Qb = Q + (size_t)bh * S * DH;
  const u16* Kb = K + (size_t)bh * S * DH;
  const u16* Vb = Vt + (size_t)bh * DH * S;
  u16* Pw = P[w];
  const int pxor = l16 & 7;

  const u16* pK[4]; u16* lK[4];
  const u16* pV[4]; u16* lV[4];
#pragma unroll
  for (int j = 0; j < 4; j++) {
    int kr = w * 16 + j * 4 + (lane >> 4);
    int ks = lane & 15;
    int kc = ks ^ (kr & 15);
    pK[j] = Kb + (size_t)kr * DH + kc * 8;
    lK[j] = &Ks[kr * 128 + ks * 8];
    int vr = w * 32 + j * 8 + (lane >> 3);
    int vs = lane & 7;
    int vc = vs ^ (vr & 7);
    pV[j] = Vb + (size_t)vr * S + vc * 8;
    lV[j] = &Vs[vr * 64 + vs * 8];
  }

  short8 aq[4];
#pragma unroll
  for (int kc = 0; kc < 4; kc++)
    aq[kc] = *(const short8*)&Qb[(size_t)(qt + l16) * DH + kc * 32 + quad * 8];

  floatx4 o[8] = {};
  float lsum = 0.0f;                 // per-lane partial: keys in own quad-subset
  const int kend = qg + 64;

  for (int k0 = 0; k0 < kend; k0 += 64) {
#pragma unroll
    for (int j = 0; j < 4; j++) async_cp16(pK[j] + (size_t)k0 * DH, lK[j]);
#pragma unroll
    for (int j = 0; j < 4; j++) async_cp16(pV[j] + k0, lV[j]);
    __syncthreads();

    // ---- S^T = K·Q^T : sc[hh] row = key k0+hh*16+quad*4+r, col = q = l16
    floatx4 sc[4] = {};
    __builtin_amdgcn_s_setprio(1);
#pragma unroll
    for (int hh = 0; hh < 4; hh++) {
      int row = hh * 16 + l16;
#pragma unroll
      for (int kc = 0; kc < 4; kc++) {
        short8 kf = *(short8*)&Ks[row * 128 + (((kc * 4 + quad) ^ l16) << 3)];
        sc[hh] = mfma16(kf, aq[kc], sc[hh]);
      }
    }
    __builtin_amdgcn_s_setprio(0);
    // ---- causal mask (only the diagonal-overlapping tile)
    if (k0 + 64 > qt) {
#pragma unroll
      for (int hh = 0; hh < 4; hh++)
#pragma unroll
        for (int r = 0; r < 4; r++) {
          int j = k0 + hh * 16 + quad * 4 + r;
          if (j > qt + l16) sc[hh][r] = -3.0e38f;
        }
    }
    // ---- direct exp2 softmax numerator; per-lane l accumulation
#pragma unroll
    for (int hh = 0; hh < 4; hh++) {
      float e0 = __builtin_amdgcn_exp2f(fminf(sc[hh][0], 44.0f));
      float e1 = __builtin_amdgcn_exp2f(fminf(sc[hh][1], 44.0f));
      float e2 = __builtin_amdgcn_exp2f(fminf(sc[hh][2], 44.0f));
      float e3 = __builtin_amdgcn_exp2f(fminf(sc[hh][3], 44.0f));
      lsum += (e0 + e1) + (e2 + e3);
      uint2 pk; pk.x = pack2(e0, e1); pk.y = pack2(e2, e3);
      // write keys hh*16+quad*4..+3 of row q=l16: 16B-unit u = 2hh + quad/2,
      // swizzled u^pxor, 8B half (quad&1)
      int su = (2 * hh + (quad >> 1)) ^ pxor;
      *(uint2*)&Pw[l16 * 64 + su * 8 + (quad & 1) * 4] = pk;
    }
    asm volatile("s_waitcnt lgkmcnt(0)" ::: "memory");
    // ---- O^T += V^T · P^T
    __builtin_amdgcn_s_setprio(1);
#pragma unroll
    for (int c = 0; c < 2; c++) {
      // read keys c*32+quad*8..+7 of row l16: 16B-unit u = 4c+quad, swizzled
      short8 pf = *(short8*)&Pw[l16 * 64 + (((4 * c + quad) ^ pxor) << 3)];
#pragma unroll
      for (int t8 = 0; t8 < 8; t8++) {
        int row = t8 * 16 + l16;
        short8 av = *(short8*)&Vs[row * 64 + (((c * 4 + quad) ^ (l16 & 7)) << 3)];
        o[t8] = mfma16(av, pf, o[t8]);
      }
    }
    __builtin_amdgcn_s_setprio(0);
    __syncthreads();
  }

  // ---- epilogue: reduce l across quads ONCE, then scale and store
  float l = lsum + __shfl_xor(lsum, 16, 64);
  l += __shfl_xor(l, 32, 64);
  float inv = __builtin_amdgcn_rcpf(l);
#pragma unroll
  for (int t8 = 0; t8 < 8; t8++) {
    uint2 pa;
    pa.x = pack2(o[t8][0] * inv, o[t8][1] * inv);
    pa.y = pack2(o[t8][2] * inv, o[t8][3] * inv);
    *(uint2*)&O[((size_t)(b * S + qt + l16)) * DM + h * DH + t8 * 16 + quad * 4] = pa;
  }
}

extern "C" void kernel_launch(void* const* d_in, const int* in_sizes, int n_in,
                              void* d_out, int out_size, void* d_ws, size_t ws_size,
                              hipStream_t stream) {
  const float* x  = (const float*)d_in[0];
  const float* Wq = (const float*)d_in[1];
  const float* Wk = (const float*)d_in[2];
  const float* Wv = (const float*)d_in[3];
  const float* Wo = (const float*)d_in[4];
  const int*   tp = (const int*)d_in[5];

  char* ws = (char*)d_ws;
  u16* Wt = (u16*)ws;
  u16* xb = (u16*)(ws + 33554432);
  u16* Qb = (u16*)(ws + 50331648);
  u16* Kb = (u16*)(ws + 67108864);
  u16* Vb = (u16*)(ws + 83886080);
  u16* Ob = (u16*)(ws + 100663296);

  conv_x_k<<<8192, 256, 0, stream>>>(x, xb);
  conv_w_k<<<dim3(64, 64, 4), 256, 0, stream>>>(Wq, Wk, Wv, Wo, Wt);
  gemm_k<<<dim3(8, 16, 3), 512, 0, stream>>>(xb, Wt, Qb, Kb, Vb, tp);
  attn_k<<<1024, 256, 0, stream>>>(Qb, Kb, Vb, Ob);
  oproj_k<<<dim3(16, 32), 256, 0, stream>>>(Ob, Wt, (float*)d_out);
}

// Round 7
// 370.138 us; speedup vs baseline: 1.1296x; 1.0222x over previous
//
#include <hip/hip_runtime.h>
#include <hip/hip_bf16.h>

#define S 2048
#define DM 2048
#define NH 16
#define DH 128

typedef __attribute__((ext_vector_type(8))) short short8;
typedef __attribute__((ext_vector_type(4))) float floatx4;
typedef unsigned short u16;
typedef unsigned int u32;

__device__ __forceinline__ u16 f2bf(float f) {
  union { float f; u32 u; } v; v.f = f;
  u32 r = v.u + 0x7fffu + ((v.u >> 16) & 1u);
  return (u16)(r >> 16);
}
// HW packed round-to-nearest-even f32x2 -> bf16x2 (v_cvt_pk_bf16_f32)
__device__ __forceinline__ u32 pack2(float lo, float hi) {
  float2 f; f.x = lo; f.y = hi;
  __hip_bfloat162 h = __float22bfloat162_rn(f);
  union { __hip_bfloat162 h; u32 u; } c; c.h = h;
  return c.u;
}

__device__ __forceinline__ floatx4 mfma16(short8 a, short8 b, floatx4 c) {
  return __builtin_amdgcn_mfma_f32_16x16x32_bf16(a, b, c, 0, 0, 0);
}

// async global -> LDS, 16B per lane. LDS dest = wave-uniform base + lane*16.
__device__ __forceinline__ void async_cp16(const u16* g, u16* l) {
  __builtin_amdgcn_global_load_lds(
      (const __attribute__((address_space(1))) void*)g,
      (__attribute__((address_space(3))) void*)l, 16, 0, 0);
}

// ---------- convert x (fp32 -> bf16), 4 elems/thread ----------
__global__ void conv_x_k(const float* __restrict__ x, u16* __restrict__ xb) {
  int gid = blockIdx.x * 256 + threadIdx.x;
  float4 v = ((const float4*)x)[gid];
  uint2 p; p.x = pack2(v.x, v.y); p.y = pack2(v.z, v.w);
  ((uint2*)xb)[gid] = p;
}

// ---------- transpose+convert weights: Wt[n*2048+k] = bf16(W[k*2048+n]) ----------
__global__ void conv_w_k(const float* __restrict__ W0, const float* __restrict__ W1,
                         const float* __restrict__ W2, const float* __restrict__ W3,
                         u16* __restrict__ out) {
  __shared__ float tile[32][33];
  const float* W = blockIdx.z == 0 ? W0 : blockIdx.z == 1 ? W1 : blockIdx.z == 2 ? W2 : W3;
  u16* O = out + (size_t)blockIdx.z * DM * DM;
  int tx = threadIdx.x & 31, ty = threadIdx.x >> 5;
  int k0 = blockIdx.y * 32, n0 = blockIdx.x * 32;
#pragma unroll
  for (int j = 0; j < 4; j++)
    tile[ty + j * 8][tx] = W[(size_t)(k0 + ty + j * 8) * DM + n0 + tx];
  __syncthreads();
#pragma unroll
  for (int j = 0; j < 4; j++)
    O[(size_t)(n0 + ty + j * 8) * DM + k0 + tx] = f2bf(tile[tx][ty + j * 8]);
}

// ---------- 256x256 bf16 MFMA GEMM for QKV + T4 counted vmcnt ----------
// 8 waves 2M x 4N (per-wave 128x64); 4 phases/K-tile. Prefetch depth 2:
// tile T stages tile T+2 INTO ITS OWN buffer p -- B in ph2 (all B-reads of
// buf p are lgkm0-drained by every wave before ph1's closing barrier), A in
// ph3 (A-reads drained before ph2's closing barrier). Boundary then waits
// vmcnt(8): retires T+1's 8 loads (issued a full tile ago, already landed)
// while T+2's 8 stay in flight across the barrier -- no drain in the main
// loop (m218: counted-vs-drain0 = +38% at 4k; r5/r6's vmcnt(0) was the gap).
// FIFO: per-thread order is B(T+2)x4, A(T+2)x4 each tile; boundary at end of
// tile X retires the 8 issued during X-1. Prologue: stage T0+T1, vmcnt(8).
// Tile 30 stages nothing (T32 absent) -> boundary vmcnt(0); tile 31 clean.
#define BM 256
#define BN 256
#define BK 64

#define BARRIER __builtin_amdgcn_s_barrier()
#define SB __builtin_amdgcn_sched_barrier(0)
#define LGKM0 asm volatile("s_waitcnt lgkmcnt(0)" ::: "memory")

#define STG_A(q, j, koff) \
  async_cp16(pAg + (size_t)(j) * 64 * DM + (koff), &As[q][soff + (j) * 4096])
#define STG_B(q, j, koff) \
  async_cp16(pBg + (size_t)(j) * 64 * DM + (koff), &Bs[q][soff + (j) * 4096])

#define PH0(p) { \
    a0k0 = *(const short8*)&As[p][awb + xk0]; \
    a0k1 = *(const short8*)&As[p][awb + xk1]; \
    a1k0 = *(const short8*)&As[p][awb + 1024 + xk0]; \
    a1k1 = *(const short8*)&As[p][awb + 1024 + xk1]; \
    a2k0 = *(const short8*)&As[p][awb + 2048 + xk0]; \
    a2k1 = *(const short8*)&As[p][awb + 2048 + xk1]; \
    a3k0 = *(const short8*)&As[p][awb + 3072 + xk0]; \
    a3k1 = *(const short8*)&As[p][awb + 3072 + xk1]; \
    b0k0 = *(const short8*)&Bs[p][bwb + xk0]; \
    b0k1 = *(const short8*)&Bs[p][bwb + xk1]; \
    b1k0 = *(const short8*)&Bs[p][bwb + 1024 + xk0]; \
    b1k1 = *(const short8*)&Bs[p][bwb + 1024 + xk1]; \
    BARRIER; LGKM0; SB; \
    __builtin_amdgcn_s_setprio(1); \
    acc[0][0] = mfma16(a0k0, b0k0, acc[0][0]); \
    acc[1][0] = mfma16(a1k0, b0k0, acc[1][0]); \
    acc[2][0] = mfma16(a2k0, b0k0, acc[2][0]); \
    acc[3][0] = mfma16(a3k0, b0k0, acc[3][0]); \
    acc[0][1] = mfma16(a0k0, b1k0, acc[0][1]); \
    acc[1][1] = mfma16(a1k0, b1k0, acc[1][1]); \
    acc[2][1] = mfma16(a2k0, b1k0, acc[2][1]); \
    acc[3][1] = mfma16(a3k0, b1k0, acc[3][1]); \
    acc[0][0] = mfma16(a0k1, b0k1, acc[0][0]); \
    acc[1][0] = mfma16(a1k1, b0k1, acc[1][0]); \
    acc[2][0] = mfma16(a2k1, b0k1, acc[2][0]); \
    acc[3][0] = mfma16(a3k1, b0k1, acc[3][0]); \
    acc[0][1] = mfma16(a0k1, b1k1, acc[0][1]); \
    acc[1][1] = mfma16(a1k1, b1k1, acc[1][1]); \
    acc[2][1] = mfma16(a2k1, b1k1, acc[2][1]); \
    acc[3][1] = mfma16(a3k1, b1k1, acc[3][1]); \
    __builtin_amdgcn_s_setprio(0); \
    BARRIER; }

#define PH1(p) { \
    b2k0 = *(const short8*)&Bs[p][bwb + 2048 + xk0]; \
    b2k1 = *(const short8*)&Bs[p][bwb + 2048 + xk1]; \
    b3k0 = *(const short8*)&Bs[p][bwb + 3072 + xk0]; \
    b3k1 = *(const short8*)&Bs[p][bwb + 3072 + xk1]; \
    BARRIER; LGKM0; SB; \
    __builtin_amdgcn_s_setprio(1); \
    acc[0][2] = mfma16(a0k0, b2k0, acc[0][2]); \
    acc[1][2] = mfma16(a1k0, b2k0, acc[1][2]); \
    acc[2][2] = mfma16(a2k0, b2k0, acc[2][2]); \
    acc[3][2] = mfma16(a3k0, b2k0, acc[3][2]); \
    acc[0][3] = mfma16(a0k0, b3k0, acc[0][3]); \
    acc[1][3] = mfma16(a1k0, b3k0, acc[1][3]); \
    acc[2][3] = mfma16(a2k0, b3k0, acc[2][3]); \
    acc[3][3] = mfma16(a3k0, b3k0, acc[3][3]); \
    acc[0][2] = mfma16(a0k1, b2k1, acc[0][2]); \
    acc[1][2] = mfma16(a1k1, b2k1, acc[1][2]); \
    acc[2][2] = mfma16(a2k1, b2k1, acc[2][2]); \
    acc[3][2] = mfma16(a3k1, b2k1, acc[3][2]); \
    acc[0][3] = mfma16(a0k1, b3k1, acc[0][3]); \
    acc[1][3] = mfma16(a1k1, b3k1, acc[1][3]); \
    acc[2][3] = mfma16(a2k1, b3k1, acc[2][3]); \
    acc[3][3] = mfma16(a3k1, b3k1, acc[3][3]); \
    __builtin_amdgcn_s_setprio(0); \
    BARRIER; }

#define PH2(p, koff2, PRE2) { \
    a0k0 = *(const short8*)&As[p][awb + 4096 + xk0]; \
    a0k1 = *(const short8*)&As[p][awb + 4096 + xk1]; \
    a1k0 = *(const short8*)&As[p][awb + 5120 + xk0]; \
    a1k1 = *(const short8*)&As[p][awb + 5120 + xk1]; \
    a2k0 = *(const short8*)&As[p][awb + 6144 + xk0]; \
    a2k1 = *(const short8*)&As[p][awb + 6144 + xk1]; \
    a3k0 = *(const short8*)&As[p][awb + 7168 + xk0]; \
    a3k1 = *(const short8*)&As[p][awb + 7168 + xk1]; \
    if (PRE2) { STG_B(p, 0, koff2); STG_B(p, 1, koff2); \
                STG_B(p, 2, koff2); STG_B(p, 3, koff2); } \
    BARRIER; LGKM0; SB; \
    __builtin_amdgcn_s_setprio(1); \
    acc[4][0] = mfma16(a0k0, b0k0, acc[4][0]); \
    acc[5][0] = mfma16(a1k0, b0k0, acc[5][0]); \
    acc[6][0] = mfma16(a2k0, b0k0, acc[6][0]); \
    acc[7][0] = mfma16(a3k0, b0k0, acc[7][0]); \
    acc[4][1] = mfma16(a0k0, b1k0, acc[4][1]); \
    acc[5][1] = mfma16(a1k0, b1k0, acc[5][1]); \
    acc[6][1] = mfma16(a2k0, b1k0, acc[6][1]); \
    acc[7][1] = mfma16(a3k0, b1k0, acc[7][1]); \
    acc[4][0] = mfma16(a0k1, b0k1, acc[4][0]); \
    acc[5][0] = mfma16(a1k1, b0k1, acc[5][0]); \
    acc[6][0] = mfma16(a2k1, b0k1, acc[6][0]); \
    acc[7][0] = mfma16(a3k1, b0k1, acc[7][0]); \
    acc[4][1] = mfma16(a0k1, b1k1, acc[4][1]); \
    acc[5][1] = mfma16(a1k1, b1k1, acc[5][1]); \
    acc[6][1] = mfma16(a2k1, b1k1, acc[6][1]); \
    acc[7][1] = mfma16(a3k1, b1k1, acc[7][1]); \
    __builtin_amdgcn_s_setprio(0); \
    BARRIER; }

#define PH3(p, koff2, PRE2, LAST) { \
    if (PRE2) { STG_A(p, 0, koff2); STG_A(p, 1, koff2); \
                STG_A(p, 2, koff2); STG_A(p, 3, koff2); } \
    SB; \
    __builtin_amdgcn_s_setprio(1); \
    acc[4][2] = mfma16(a0k0, b2k0, acc[4][2]); \
    acc[5][2] = mfma16(a1k0, b2k0, acc[5][2]); \
    acc[6][2] = mfma16(a2k0, b2k0, acc[6][2]); \
    acc[7][2] = mfma16(a3k0, b2k0, acc[7][2]); \
    acc[4][3] = mfma16(a0k0, b3k0, acc[4][3]); \
    acc[5][3] = mfma16(a1k0, b3k0, acc[5][3]); \
    acc[6][3] = mfma16(a2k0, b3k0, acc[6][3]); \
    acc[7][3] = mfma16(a3k0, b3k0, acc[7][3]); \
    acc[4][2] = mfma16(a0k1, b2k1, acc[4][2]); \
    acc[5][2] = mfma16(a1k1, b2k1, acc[5][2]); \
    acc[6][2] = mfma16(a2k1, b2k1, acc[6][2]); \
    acc[7][2] = mfma16(a3k1, b2k1, acc[7][2]); \
    acc[4][3] = mfma16(a0k1, b3k1, acc[4][3]); \
    acc[5][3] = mfma16(a1k1, b3k1, acc[5][3]); \
    acc[6][3] = mfma16(a2k1, b3k1, acc[6][3]); \
    acc[7][3] = mfma16(a3k1, b3k1, acc[7][3]); \
    __builtin_amdgcn_s_setprio(0); SB; \
    if (!LAST) { \
      if (PRE2) { asm volatile("s_waitcnt vmcnt(8)" ::: "memory"); } \
      else      { asm volatile("s_waitcnt vmcnt(0)" ::: "memory"); } \
      BARRIER; SB; } }

#define TILE(p, koff2, PRE2, LAST) \
    PH0(p) PH1(p) PH2(p, koff2, PRE2) PH3(p, koff2, PRE2, LAST)

__global__ __launch_bounds__(512, 2)
void gemm_k(const u16* __restrict__ A, const u16* __restrict__ Wt,
            u16* __restrict__ oQ, u16* __restrict__ oK, u16* __restrict__ oV,
            const int* __restrict__ tp)
{
  __shared__ u16 As[2][BM * BK];   // 2 x 32 KiB
  __shared__ u16 Bs[2][BN * BK];   // 2 x 32 KiB -> 128 KiB total
  const int t = threadIdx.x;
  const int w = t >> 6, lane = t & 63;
  const int l16 = lane & 15, quad = lane >> 4;
  const int wr = w >> 2, wc = w & 3;     // 2M x 4N waves, 128x64 each
  const int m0 = blockIdx.y * BM, n0 = blockIdx.x * BN;
  const u16* Bt = Wt + (size_t)blockIdx.z * DM * DM;

  // staging: unit u = t + j*512 -> row u>>3 = (t>>3)+j*64, stored granule u&7
  // holds source granule (u&7)^(row&7); both are j-invariant.
  const int srow = t >> 3;
  const int sc = ((t & 7) ^ (srow & 7)) * 8;
  const u16* pAg = A + (size_t)(m0 + srow) * DM + sc;
  const u16* pBg = Bt + (size_t)(n0 + srow) * DM + sc;
  const int soff = t * 8;

  // fragment read offsets (u16 units); row&7 == l16&7 (row bases mult. of 16)
  const int awb = (wr * 128 + l16) * 64;
  const int bwb = (wc * 64 + l16) * 64;
  const int xk0 = ((quad) ^ (l16 & 7)) << 3;
  const int xk1 = ((4 + quad) ^ (l16 & 7)) << 3;

  floatx4 acc[8][4] = {};
  short8 a0k0, a0k1, a1k0, a1k1, a2k0, a2k1, a3k0, a3k1;
  short8 b0k0, b0k1, b1k0, b1k1, b2k0, b2k1, b3k0, b3k1;

  // ---- prologue: stage tile 0 -> buf0 and tile 1 -> buf1 (16 loads/thread);
  // vmcnt(8) waits tile 0 only, tile 1's 8 stay in flight.
#pragma unroll
  for (int j = 0; j < 4; j++) STG_A(0, j, 0);
#pragma unroll
  for (int j = 0; j < 4; j++) STG_B(0, j, 0);
#pragma unroll
  for (int j = 0; j < 4; j++) STG_A(1, j, BK);
#pragma unroll
  for (int j = 0; j < 4; j++) STG_B(1, j, BK);
  SB;
  asm volatile("s_waitcnt vmcnt(8)" ::: "memory");
  BARRIER; SB;

  for (int it = 0; it < 15; ++it) {
    const int kE = (2 * it + 2) * 64;    // tile 2it   stages tile 2it+2 -> buf0
    const int kO = (2 * it + 3) * 64;    // tile 2it+1 stages tile 2it+3 -> buf1
    TILE(0, kE, 1, 0)
    TILE(1, kO, 1, 0)
  }
  TILE(0, 0, 0, 0)                       // tile 30: no stage, drain for tile 31
  TILE(1, 0, 0, 1)                       // tile 31: clean

  // ---- epilogue: per-wave 128x64; m = m0+wr*128+mi*16+quad*4+r, n = n0+wc*64+ni*16+l16
  const int mwb = m0 + wr * 128;
  const int nwb = n0 + wc * 64;
  if ((int)blockIdx.z == 2) {
#pragma unroll
    for (int mi = 0; mi < 8; mi++) {
      int m = mwb + mi * 16 + quad * 4;
      int b = m >> 11, s = m & (S - 1);
#pragma unroll
      for (int ni = 0; ni < 4; ni++) {
        int f = nwb + ni * 16 + l16;
        int h = f >> 7, dh = f & (DH - 1);
        uint2 pk; pk.x = pack2(acc[mi][ni][0], acc[mi][ni][1]);
        pk.y = pack2(acc[mi][ni][2], acc[mi][ni][3]);
        *(uint2*)&oV[((size_t)(b * NH + h) * DH + dh) * S + s] = pk;
      }
    }
  } else {
    // RoPE fused; for Q (z==0) also fold 1/sqrt(dk)*log2(e) into the value
    u16* Out = ((int)blockIdx.z == 0) ? oQ : oK;
    const float qs = ((int)blockIdx.z == 0) ? 0.12752780f : 1.0f;
#pragma unroll
    for (int mi = 0; mi < 8; mi++) {
#pragma unroll
      for (int r = 0; r < 4; r++) {
        int m = mwb + mi * 16 + quad * 4 + r;
        int b = m >> 11, s = m & (S - 1);
        int ps = tp[s];
#pragma unroll
        for (int ni = 0; ni < 4; ni++) {
          int f = nwb + ni * 16 + l16;
          int h = f >> 7, dh = f & (DH - 1);
          float own = acc[mi][ni][r];
          float oth = __shfl_xor(own, 1, 64);
          float fr = __expf((float)(dh & ~1) * (-9.210340371976184f / 128.0f));
          float ang = (float)ps * fr;
          float sn, cs; __sincosf(ang, &sn, &cs);
          float res = (dh & 1) ? (oth * sn + own * cs) : (own * cs - oth * sn);
          Out[((size_t)(b * NH + h) * S + s) * DH + dh] = f2bf(res * qs);
        }
      }
    }
  }
}

// ---------- O-projection: 128x128 bf16 MFMA GEMM, 4 blocks/CU (round-0 config) ----------
// Grid 16x32 = 512 blocks -> 2 full rounds at 4 blocks/CU (no idle-CU tail;
// r5's 256^2 O-proj left half the machine idle: 69 us vs 48 us here).
__global__ __launch_bounds__(256, 4)
void oproj_k(const u16* __restrict__ A, const u16* __restrict__ Wt,
             float* __restrict__ oO)
{
  __shared__ u16 As2[128 * 32];
  __shared__ u16 Bs2[128 * 32];
  const int t = threadIdx.x;
  const int w = t >> 6, lane = t & 63;
  const int l16 = lane & 15, quad = lane >> 4;
  const int m0 = blockIdx.y * 128, n0 = blockIdx.x * 128;
  const int wm = (w >> 1) * 64, wn = (w & 1) * 64;
  const u16* Bt = Wt + (size_t)3 * DM * DM;

  const u16* pA[2]; const u16* pB[2]; u16* lA[2]; u16* lB[2];
#pragma unroll
  for (int i = 0; i < 2; i++) {
    int unit = i * 256 + t;
    int row = unit >> 2, s = unit & 3;
    int c = s ^ ((row >> 1) & 3);
    pA[i] = A + (size_t)(m0 + row) * DM + c * 8;
    pB[i] = Bt + (size_t)(n0 + row) * DM + c * 8;
    lA[i] = &As2[unit * 8];
    lB[i] = &Bs2[unit * 8];
  }

  floatx4 acc[4][4] = {};

  for (int k0 = 0; k0 < DM; k0 += 32) {
#pragma unroll
    for (int i = 0; i < 2; i++) {
      async_cp16(pA[i] + k0, lA[i]);
      async_cp16(pB[i] + k0, lB[i]);
    }
    __syncthreads();
    short8 af[4], bfr[4];
#pragma unroll
    for (int i = 0; i < 4; i++) {
      int row = wm + i * 16 + l16;
      af[i] = *(short8*)&As2[(row * 4 + (quad ^ ((row >> 1) & 3))) * 8];
    }
#pragma unroll
    for (int i = 0; i < 4; i++) {
      int row = wn + i * 16 + l16;
      bfr[i] = *(short8*)&Bs2[(row * 4 + (quad ^ ((row >> 1) & 3))) * 8];
    }
#pragma unroll
    for (int mi = 0; mi < 4; mi++)
#pragma unroll
      for (int ni = 0; ni < 4; ni++)
        acc[mi][ni] = mfma16(af[mi], bfr[ni], acc[mi][ni]);
    __syncthreads();
  }

#pragma unroll
  for (int mi = 0; mi < 4; mi++) {
    int m = m0 + wm + mi * 16 + quad * 4;
#pragma unroll
    for (int ni = 0; ni < 4; ni++) {
      int n = n0 + wn + ni * 16 + l16;
#pragma unroll
      for (int r = 0; r < 4; r++)
        oO[(size_t)(m + r) * DM + n] = acc[mi][ni][r];
    }
  }
}

// ---------- causal flash attention v7 + T5 setprio: 16 q/wave, 40KB LDS ----------
// P is unpadded (16x64) with 16B-granule XOR swizzle -> Ks+Vs+P = 40960 B exactly,
// 4 blocks/CU at __launch_bounds__(256,4). setprio(1) around QK and PV MFMA
// clusters (T5: +4-7% measured on attn with independent blocks, m191).
__global__ __launch_bounds__(256, 4)
void attn_k(const u16* __restrict__ Q, const u16* __restrict__ K,
            const u16* __restrict__ Vt, u16* __restrict__ O)
{
  __shared__ u16 Ks[64 * 128];   // key-major, swizzle: unit r*16 + (c ^ (r&15))
  __shared__ u16 Vs[128 * 64];   // dh-major,  swizzle: unit r*8  + (c ^ (r&7))
  __shared__ u16 P[4][16 * 64];  // per-wave 16 q x 64 keys, 16B-XOR-swizzled
  const int t = threadIdx.x, w = t >> 6, lane = t & 63;
  const int l16 = lane & 15, quad = lane >> 4;
  const int task = blockIdx.x;
  const int bh = task & 31, b = bh >> 4, h = bh & 15;
  const int g = 31 - (task >> 5);        // big groups dispatch first (LPT)
  const int qg = g * 64;
  const int qt = qg + w * 16;
  const u16* Qb = Q + (size_t)bh * S * DH;
  const u16* Kb = K + (size_t)bh * S * DH;
  const u16* Vb = Vt + (size_t)bh * DH * S;
  u16* Pw = P[w];
  const int pxor = l16 & 7;

  const u16* pK[4]; u16* lK[4];
  const u16* pV[4]; u16* lV[4];
#pragma unroll
  for (int j = 0; j < 4; j++) {
    int kr = w * 16 + j * 4 + (lane >> 4);
    int ks = lane & 15;
    int kc = ks ^ (kr & 15);
    pK[j] = Kb + (size_t)kr * DH + kc * 8;
    lK[j] = &Ks[kr * 128 + ks * 8];
    int vr = w * 32 + j * 8 + (lane >> 3);
    int vs = lane & 7;
    int vc = vs ^ (vr & 7);
    pV[j] = Vb + (size_t)vr * S + vc * 8;
    lV[j] = &Vs[vr * 64 + vs * 8];
  }

  short8 aq[4];
#pragma unroll
  for (int kc = 0; kc < 4; kc++)
    aq[kc] = *(const short8*)&Qb[(size_t)(qt + l16) * DH + kc * 32 + quad * 8];

  floatx4 o[8] = {};
  float lsum = 0.0f;                 // per-lane partial: keys in own quad-subset
  const int kend = qg + 64;

  for (int k0 = 0; k0 < kend; k0 += 64) {
#pragma unroll
    for (int j = 0; j < 4; j++) async_cp16(pK[j] + (size_t)k0 * DH, lK[j]);
#pragma unroll
    for (int j = 0; j < 4; j++) async_cp16(pV[j] + k0, lV[j]);
    __syncthreads();

    // ---- S^T = K·Q^T : sc[hh] row = key k0+hh*16+quad*4+r, col = q = l16
    floatx4 sc[4] = {};
    __builtin_amdgcn_s_setprio(1);
#pragma unroll
    for (int hh = 0; hh < 4; hh++) {
      int row = hh * 16 + l16;
#pragma unroll
      for (int kc = 0; kc < 4; kc++) {
        short8 kf = *(short8*)&Ks[row * 128 + (((kc * 4 + quad) ^ l16) << 3)];
        sc[hh] = mfma16(kf, aq[kc], sc[hh]);
      }
    }
    __builtin_amdgcn_s_setprio(0);
    // ---- causal mask (only the diagonal-overlapping tile)
    if (k0 + 64 > qt) {
#pragma unroll
      for (int hh = 0; hh < 4; hh++)
#pragma unroll
        for (int r = 0; r < 4; r++) {
          int j = k0 + hh * 16 + quad * 4 + r;
          if (j > qt + l16) sc[hh][r] = -3.0e38f;
        }
    }
    // ---- direct exp2 softmax numerator; per-lane l accumulation
#pragma unroll
    for (int hh = 0; hh < 4; hh++) {
      float e0 = __builtin_amdgcn_exp2f(fminf(sc[hh][0], 44.0f));
      float e1 = __builtin_amdgcn_exp2f(fminf(sc[hh][1], 44.0f));
      float e2 = __builtin_amdgcn_exp2f(fminf(sc[hh][2], 44.0f));
      float e3 = __builtin_amdgcn_exp2f(fminf(sc[hh][3], 44.0f));
      lsum += (e0 + e1) + (e2 + e3);
      uint2 pk; pk.x = pack2(e0, e1); pk.y = pack2(e2, e3);
      // write keys hh*16+quad*4..+3 of row q=l16: 16B-unit u = 2hh + quad/2,
      // swizzled u^pxor, 8B half (quad&1)
      int su = (2 * hh + (quad >> 1)) ^ pxor;
      *(uint2*)&Pw[l16 * 64 + su * 8 + (quad & 1) * 4] = pk;
    }
    asm volatile("s_waitcnt lgkmcnt(0)" ::: "memory");
    // ---- O^T += V^T · P^T
    __builtin_amdgcn_s_setprio(1);
#pragma unroll
    for (int c = 0; c < 2; c++) {
      // read keys c*32+quad*8..+7 of row l16: 16B-unit u = 4c+quad, swizzled
      short8 pf = *(short8*)&Pw[l16 * 64 + (((4 * c + quad) ^ pxor) << 3)];
#pragma unroll
      for (int t8 = 0; t8 < 8; t8++) {
        int row = t8 * 16 + l16;
        short8 av = *(short8*)&Vs[row * 64 + (((c * 4 + quad) ^ (l16 & 7)) << 3)];
        o[t8] = mfma16(av, pf, o[t8]);
      }
    }
    __builtin_amdgcn_s_setprio(0);
    __syncthreads();
  }

  // ---- epilogue: reduce l across quads ONCE, then scale and store
  float l = lsum + __shfl_xor(lsum, 16, 64);
  l += __shfl_xor(l, 32, 64);
  float inv = __builtin_amdgcn_rcpf(l);
#pragma unroll
  for (int t8 = 0; t8 < 8; t8++) {
    uint2 pa;
    pa.x = pack2(o[t8][0] * inv, o[t8][1] * inv);
    pa.y = pack2(o[t8][2] * inv, o[t8][3] * inv);
    *(uint2*)&O[((size_t)(b * S + qt + l16)) * DM + h * DH + t8 * 16 + quad * 4] = pa;
  }
}

extern "C" void kernel_launch(void* const* d_in, const int* in_sizes, int n_in,
                              void* d_out, int out_size, void* d_ws, size_t ws_size,
                              hipStream_t stream) {
  const float* x  = (const float*)d_in[0];
  const float* Wq = (const float*)d_in[1];
  const float* Wk = (const float*)d_in[2];
  const float* Wv = (const float*)d_in[3];
  const float* Wo = (const float*)d_in[4];
  const int*   tp = (const int*)d_in[5];

  char* ws = (char*)d_ws;
  u16* Wt = (u16*)ws;
  u16* xb = (u16*)(ws + 33554432);
  u16* Qb = (u16*)(ws + 50331648);
  u16* Kb = (u16*)(ws + 67108864);
  u16* Vb = (u16*)(ws + 83886080);
  u16* Ob = (u16*)(ws + 100663296);

  conv_x_k<<<8192, 256, 0, stream>>>(x, xb);
  conv_w_k<<<dim3(64, 64, 4), 256, 0, stream>>>(Wq, Wk, Wv, Wo, Wt);
  gemm_k<<<dim3(8, 16, 3), 512, 0, stream>>>(xb, Wt, Qb, Kb, Vb, tp);
  attn_k<<<1024, 256, 0, stream>>>(Qb, Kb, Vb, Ob);
  oproj_k<<<dim3(16, 32), 256, 0, stream>>>(Ob, Wt, (float*)d_out);
}